// Round 6
// baseline (1076.737 us; speedup 1.0000x reference)
//
#include <hip/hip_runtime.h>
#include <stdint.h>

// Problem constants
#define B_   16
#define N_   4096
#define M_   1024
#define NT   (B_*M_*32)      // 524288 samples
#define BM   (B_*M_)         // 16384 (b,m) groups

typedef unsigned short u16;
typedef unsigned long long u64;

__device__ __forceinline__ float bf2f(u16 u){
    return __uint_as_float(((unsigned int)u) << 16);
}
__device__ __forceinline__ u16 f2bf(float f){
    unsigned int u = __float_as_uint(f);
    return (u16)((u + 0x7FFFu + ((u >> 16) & 1u)) >> 16);
}
__device__ __forceinline__ u64 umin64(u64 a, u64 b){ return a < b ? a : b; }

// ---------------------------------------------------------------------------
// features [B][64][N] f32 -> featT [B][N][64] f32
// ---------------------------------------------------------------------------
__global__ __launch_bounds__(256) void k_feat(const float* __restrict__ feat,
                                              float* __restrict__ featT){
    __shared__ float tile[64][65];
    int b  = blockIdx.y;
    int n0 = blockIdx.x * 64;
    for (int t = threadIdx.x; t < 4096; t += 256){
        int c = t >> 6, n = t & 63;
        tile[c][n] = feat[((size_t)(b*64 + c))*N_ + n0 + n];
    }
    __syncthreads();
    for (int t = threadIdx.x; t < 4096; t += 256){
        int n = t >> 6, c = t & 63;
        featT[((size_t)(b*N_) + n0 + n)*64 + c] = tile[c][n];
    }
}

// ---------------------------------------------------------------------------
// exact KNN (32 smallest of 4096) by iterative min-extraction on u64 keys
// key = (f32 d2 bits << 32) | index -> unique keys, exact order, lowest-index
// tie-break (matches top_k). One block (256 thr) per query.
// ---------------------------------------------------------------------------
__global__ __launch_bounds__(256) void k_knn(const float* __restrict__ locF,
                                             const float* __restrict__ nlocF,
                                             int* __restrict__ idxOut){
    const int tid  = threadIdx.x;
    const int lane = tid & 63, wave = tid >> 6;
    const int q    = blockIdx.x;
    const int b    = q >> 10, m = q & 1023;

    float qx = nlocF[(size_t)(b*M_ + m)*3 + 0];
    float qy = nlocF[(size_t)(b*M_ + m)*3 + 1];
    float qz = nlocF[(size_t)(b*M_ + m)*3 + 2];
    float y2 = __fadd_rn(__fadd_rn(__fmul_rn(qx,qx), __fmul_rn(qy,qy)), __fmul_rn(qz,qz));

    u64 key[16];
    const float* lb = locF + (size_t)b*N_*3;
    #pragma unroll
    for (int i = 0; i < 16; ++i){
        int n = i*256 + tid;
        float lx = lb[n*3+0], ly = lb[n*3+1], lz = lb[n*3+2];
        float x2 = __fadd_rn(__fadd_rn(__fmul_rn(lx,lx), __fmul_rn(ly,ly)), __fmul_rn(lz,lz));
        float dt = __fadd_rn(__fadd_rn(__fmul_rn(qx,lx), __fmul_rn(qy,ly)), __fmul_rn(qz,lz));
        float d2 = __fsub_rn(__fadd_rn(y2, x2), __fmul_rn(2.0f, dt));
        d2 = fmaxf(d2, 0.0f);                  // uint order == float order
        key[i] = (((u64)__float_as_uint(d2)) << 32) | (unsigned int)n;
    }

    u64 myMin = key[0];
    #pragma unroll
    for (int i = 1; i < 16; ++i) myMin = umin64(myMin, key[i]);

    __shared__ u64 wmin[4];

    for (int r = 0; r < 32; ++r){
        u64 v = myMin;
        #pragma unroll
        for (int st = 32; st >= 1; st >>= 1)
            v = umin64(v, __shfl_down(v, st, 64));
        if (lane == 0) wmin[wave] = v;
        __syncthreads();
        u64 gbest = umin64(umin64(wmin[0], wmin[1]), umin64(wmin[2], wmin[3]));
        if (tid == 0) idxOut[(size_t)q*32 + r] = (int)(gbest & 0xFFFFFFFFu);
        if (myMin == gbest){                   // unique owner
            u64 nm = ~0ull;
            #pragma unroll
            for (int i = 0; i < 16; ++i){
                if (key[i] == gbest) key[i] = ~0ull;
                nm = umin64(nm, key[i]);
            }
            myMin = nm;
        }
        __syncthreads();
    }
}

// ---------------------------------------------------------------------------
// device helpers (f32 inputs)
// ---------------------------------------------------------------------------
__device__ __forceinline__ void gather_conv1(int s, const int* __restrict__ idx,
                                             const float* __restrict__ locF,
                                             const float* __restrict__ nlocF,
                                             const float* __restrict__ featT,
                                             const float* Wl, float* acc){
    int b = s >> 15;
    int m = (s >> 5) & 1023;
    int n = idx[s];
    if ((unsigned)n >= N_) n = 0;              // fault armor

    float r0 = locF[(size_t)(b*N_ + n)*3 + 0] - nlocF[(size_t)(b*M_ + m)*3 + 0];
    float r1 = locF[(size_t)(b*N_ + n)*3 + 1] - nlocF[(size_t)(b*M_ + m)*3 + 1];
    float r2 = locF[(size_t)(b*N_ + n)*3 + 2] - nlocF[(size_t)(b*M_ + m)*3 + 2];

    #pragma unroll
    for (int o = 0; o < 64; ++o)
        acc[o] = Wl[o]*r0 + Wl[64 + o]*r1 + Wl[128 + o]*r2;

    const float4* frow = (const float4*)(featT + ((size_t)(b*N_) + n)*64);
    #pragma unroll
    for (int c4 = 0; c4 < 16; ++c4){
        float4 fv = frow[c4];
        float f[4] = {fv.x, fv.y, fv.z, fv.w};
        #pragma unroll
        for (int j = 0; j < 4; ++j){
            const float* wc = &Wl[(3 + c4*4 + j)*64];
            float v = f[j];
            #pragma unroll
            for (int o = 0; o < 64; ++o) acc[o] = fmaf(wc[o], v, acc[o]);
        }
    }
}

// block-wide per-channel sum/sumsq of acc[64] -> global atomics
__device__ __forceinline__ void blockStats64(const float* acc, float* gsum, float* gsq,
                                             float* ldsS, float* ldsQ){
    const int lane = threadIdx.x & 63, wave = threadIdx.x >> 6;
    #pragma unroll
    for (int o = 0; o < 64; ++o){
        float sm = acc[o], sq = acc[o]*acc[o];
        #pragma unroll
        for (int st = 32; st >= 1; st >>= 1){
            sm += __shfl_down(sm, st, 64);
            sq += __shfl_down(sq, st, 64);
        }
        if (lane == 0){ ldsS[wave*64 + o] = sm; ldsQ[wave*64 + o] = sq; }
    }
    __syncthreads();
    if (threadIdx.x < 64){
        int o = threadIdx.x;
        float sm = ldsS[o] + ldsS[64+o] + ldsS[128+o] + ldsS[192+o];
        float sq = ldsQ[o] + ldsQ[64+o] + ldsQ[128+o] + ldsQ[192+o];
        atomicAdd(&gsum[o], sm); atomicAdd(&gsq[o], sq);
    }
}

// conv3 epilogue: per-(b,m) 32-lane max/min of raw y3 -> gmax/gmin [o][BM],
// plus per-channel sum/sumsq atomics.
__device__ __forceinline__ void epilogue128(const float* acc, int s,
                                            float* __restrict__ gmax, float* __restrict__ gmin,
                                            float* gsum, float* gsq,
                                            float* ldsS, float* ldsQ){
    const int lane = threadIdx.x & 63, wave = threadIdx.x >> 6;
    const bool wr = ((threadIdx.x & 31) == 0);
    const size_t g = (size_t)(s >> 5);           // group = b*M + m
    #pragma unroll
    for (int o = 0; o < 128; ++o){
        float v = acc[o];
        float mx = v, mn = v, sm = v, sq = v*v;
        #pragma unroll
        for (int st = 16; st >= 1; st >>= 1){
            mx = fmaxf(mx, __shfl_down(mx, st, 64));
            mn = fminf(mn, __shfl_down(mn, st, 64));
        }
        #pragma unroll
        for (int st = 32; st >= 1; st >>= 1){
            sm += __shfl_down(sm, st, 64);
            sq += __shfl_down(sq, st, 64);
        }
        if (wr){ gmax[(size_t)o*BM + g] = mx; gmin[(size_t)o*BM + g] = mn; }
        if (lane == 0){ ldsS[wave*128 + o] = sm; ldsQ[wave*128 + o] = sq; }
    }
    __syncthreads();
    if (threadIdx.x < 128){
        int o = threadIdx.x;
        float sm = ldsS[o] + ldsS[128+o] + ldsS[256+o] + ldsS[384+o];
        float sq = ldsQ[o] + ldsQ[128+o] + ldsQ[256+o] + ldsQ[384+o];
        atomicAdd(&gsum[o], sm); atomicAdd(&gsq[o], sq);
    }
}

// ---------------------------------------------------------------------------
// FAST path kernels (y1,y2 materialized as bf16 [64][NT])
// ---------------------------------------------------------------------------
__global__ __launch_bounds__(256) void k_conv1(const int* __restrict__ idx,
                                               const float* __restrict__ locF,
                                               const float* __restrict__ nlocF,
                                               const float* __restrict__ featT,
                                               const float* __restrict__ W1,
                                               u16* __restrict__ y1){
    __shared__ float Wl[67*64];                 // [c][o]
    for (int t = threadIdx.x; t < 67*64; t += 256){
        int c = t >> 6, o = t & 63;
        Wl[t] = W1[o*67 + c];
    }
    __syncthreads();
    int s = blockIdx.x*256 + threadIdx.x;
    float acc[64];
    gather_conv1(s, idx, locF, nlocF, featT, Wl, acc);
    #pragma unroll
    for (int o = 0; o < 64; ++o) y1[(size_t)o*NT + s] = f2bf(acc[o]);
}

__global__ __launch_bounds__(256) void k_conv2(const u16* __restrict__ yin,
                                               const float* __restrict__ W2,
                                               const float* __restrict__ prm,
                                               u16* __restrict__ yout){
    __shared__ float Wl[64*64];
    __shared__ float sS[64], sT[64];
    for (int t = threadIdx.x; t < 64*64; t += 256){
        int c = t >> 6, o = t & 63;
        Wl[t] = W2[o*64 + c];
    }
    if (threadIdx.x < 64){ sS[threadIdx.x] = prm[threadIdx.x]; sT[threadIdx.x] = prm[64 + threadIdx.x]; }
    __syncthreads();

    size_t s = (size_t)blockIdx.x*256 + threadIdx.x;
    float acc[64];
    #pragma unroll
    for (int o = 0; o < 64; ++o) acc[o] = 0.0f;
    for (int c = 0; c < 64; ++c){
        float v = fmaxf(fmaf(bf2f(yin[(size_t)c*NT + s]), sS[c], sT[c]), 0.0f);
        const float* wc = &Wl[c*64];
        #pragma unroll
        for (int o = 0; o < 64; ++o) acc[o] = fmaf(wc[o], v, acc[o]);
    }
    #pragma unroll
    for (int o = 0; o < 64; ++o) yout[(size_t)o*NT + s] = f2bf(acc[o]);
}

__global__ __launch_bounds__(256) void k_conv3mm(const u16* __restrict__ yin,
                                                 const float* __restrict__ W3,
                                                 const float* __restrict__ prm,
                                                 float* __restrict__ gsum, float* __restrict__ gsq,
                                                 float* __restrict__ gmax, float* __restrict__ gmin){
    __shared__ float Wl[64*128];
    __shared__ float sS[64], sT[64];
    __shared__ float ldsS[512], ldsQ[512];
    for (int t = threadIdx.x; t < 64*128; t += 256){
        int c = t >> 7, o = t & 127;
        Wl[t] = W3[o*64 + c];
    }
    if (threadIdx.x < 64){ sS[threadIdx.x] = prm[threadIdx.x]; sT[threadIdx.x] = prm[64 + threadIdx.x]; }
    __syncthreads();

    int s = blockIdx.x*256 + threadIdx.x;
    float acc[128];
    #pragma unroll
    for (int o = 0; o < 128; ++o) acc[o] = 0.0f;
    for (int c = 0; c < 64; ++c){
        float v = fmaxf(fmaf(bf2f(yin[(size_t)c*NT + s]), sS[c], sT[c]), 0.0f);
        const float* wc = &Wl[c*128];
        #pragma unroll
        for (int o = 0; o < 128; ++o) acc[o] = fmaf(wc[o], v, acc[o]);
    }
    epilogue128(acc, s, gmax, gmin, gsum, gsq, ldsS, ldsQ);
}

// per-channel sum/sumsq over stored y (bf16 channel-major)
__global__ __launch_bounds__(256) void k_stats(const u16* __restrict__ y,
                                               float* __restrict__ sum,
                                               float* __restrict__ sumsq){
    int c = blockIdx.x, chunk = blockIdx.y;
    size_t base = (size_t)c*NT + (size_t)chunk*16384;
    float s = 0.0f, qq = 0.0f;
    for (int i = threadIdx.x; i < 16384; i += 256){
        float v = bf2f(y[base + i]);
        s += v; qq = fmaf(v, v, qq);
    }
    #pragma unroll
    for (int off = 32; off > 0; off >>= 1){
        s  += __shfl_down(s,  off, 64);
        qq += __shfl_down(qq, off, 64);
    }
    __shared__ float aS[4], aQ[4];
    int wave = threadIdx.x >> 6, lane = threadIdx.x & 63;
    if (lane == 0){ aS[wave] = s; aQ[wave] = qq; }
    __syncthreads();
    if (threadIdx.x == 0){
        atomicAdd(&sum[c],   aS[0] + aS[1] + aS[2] + aS[3]);
        atomicAdd(&sumsq[c], aQ[0] + aQ[1] + aQ[2] + aQ[3]);
    }
}

// fold BN into affine: s = g*rsqrt(var+eps), t = b - mu*s
__global__ void k_fold(const float* __restrict__ sum, const float* __restrict__ sumsq,
                       const float* __restrict__ gW, const float* __restrict__ bW,
                       float* __restrict__ prm, int C){
    int c = threadIdx.x;
    if (c < C){
        const float inv = 1.0f / (float)NT;
        float mu  = sum[c] * inv;
        float var = sumsq[c] * inv - mu*mu;
        float sc  = gW[c] / sqrtf(var + 1e-5f);
        prm[c]     = sc;
        prm[C + c] = bW[c] - mu*sc;
    }
}

// out[b][o][m] = ReLU(s * (s>=0 ? gmax : gmin) + t)   -- FLOAT32 output
__global__ __launch_bounds__(256) void k_final(const float* __restrict__ gmax,
                                               const float* __restrict__ gmin,
                                               const float* __restrict__ prm,
                                               float* __restrict__ out){
    int bo = blockIdx.y;
    int b = bo >> 7, o = bo & 127;
    int m = blockIdx.x*256 + threadIdx.x;
    float sc = prm[o], tt = prm[128 + o];
    size_t i = (size_t)o*BM + b*M_ + m;
    float v = (sc >= 0.0f) ? gmax[i] : gmin[i];
    out[((size_t)(b*128 + o))*M_ + m] = fmaxf(fmaf(v, sc, tt), 0.0f);
}

// ---------------------------------------------------------------------------
// MIN path kernels (recompute chain, all-f32 registers; only idx/featT/minmax persist)
// ---------------------------------------------------------------------------
__global__ __launch_bounds__(256) void k_q1(const int* __restrict__ idx,
                                            const float* __restrict__ locF,
                                            const float* __restrict__ nlocF,
                                            const float* __restrict__ featT,
                                            const float* __restrict__ W1,
                                            float* __restrict__ gsum, float* __restrict__ gsq){
    __shared__ float sbuf[67*64];
    __shared__ float ldsS[256], ldsQ[256];
    for (int t = threadIdx.x; t < 67*64; t += 256){
        int c = t >> 6, o = t & 63;
        sbuf[t] = W1[o*67 + c];
    }
    __syncthreads();
    int s = blockIdx.x*256 + threadIdx.x;
    float acc[64];
    gather_conv1(s, idx, locF, nlocF, featT, sbuf, acc);
    blockStats64(acc, gsum, gsq, ldsS, ldsQ);
}

__global__ __launch_bounds__(256) void k_q2(const int* __restrict__ idx,
                                            const float* __restrict__ locF,
                                            const float* __restrict__ nlocF,
                                            const float* __restrict__ featT,
                                            const float* __restrict__ W1,
                                            const float* __restrict__ W2,
                                            const float* __restrict__ prm1,
                                            float* __restrict__ gsum, float* __restrict__ gsq){
    __shared__ float sbuf[67*64];
    __shared__ float sS1[64], sT1[64];
    __shared__ float ldsS[256], ldsQ[256];
    for (int t = threadIdx.x; t < 67*64; t += 256){
        int c = t >> 6, o = t & 63;
        sbuf[t] = W1[o*67 + c];
    }
    if (threadIdx.x < 64){ sS1[threadIdx.x] = prm1[threadIdx.x]; sT1[threadIdx.x] = prm1[64 + threadIdx.x]; }
    __syncthreads();
    int s = blockIdx.x*256 + threadIdx.x;
    float acc1[64];
    gather_conv1(s, idx, locF, nlocF, featT, sbuf, acc1);
    __syncthreads();
    for (int t = threadIdx.x; t < 64*64; t += 256){
        int c = t >> 6, o = t & 63;
        sbuf[c*64 + o] = W2[o*64 + c];
    }
    __syncthreads();
    float acc2[64];
    #pragma unroll
    for (int o = 0; o < 64; ++o) acc2[o] = 0.0f;
    #pragma unroll
    for (int c = 0; c < 64; ++c){
        float v = fmaxf(fmaf(acc1[c], sS1[c], sT1[c]), 0.0f);
        const float* wc = &sbuf[c*64];
        #pragma unroll
        for (int o = 0; o < 64; ++o) acc2[o] = fmaf(wc[o], v, acc2[o]);
    }
    blockStats64(acc2, gsum, gsq, ldsS, ldsQ);
}

__global__ __launch_bounds__(256) void k_q3(const int* __restrict__ idx,
                                            const float* __restrict__ locF,
                                            const float* __restrict__ nlocF,
                                            const float* __restrict__ featT,
                                            const float* __restrict__ W1,
                                            const float* __restrict__ W2,
                                            const float* __restrict__ W3,
                                            const float* __restrict__ prm1,
                                            const float* __restrict__ prm2,
                                            float* __restrict__ gsum, float* __restrict__ gsq,
                                            float* __restrict__ gmax, float* __restrict__ gmin){
    __shared__ float sbuf[64*128];
    __shared__ float sS1[64], sT1[64], sS2[64], sT2[64];
    __shared__ float ldsS[512], ldsQ[512];
    for (int t = threadIdx.x; t < 67*64; t += 256){
        int c = t >> 6, o = t & 63;
        sbuf[t] = W1[o*67 + c];
    }
    if (threadIdx.x < 64){
        sS1[threadIdx.x] = prm1[threadIdx.x]; sT1[threadIdx.x] = prm1[64 + threadIdx.x];
        sS2[threadIdx.x] = prm2[threadIdx.x]; sT2[threadIdx.x] = prm2[64 + threadIdx.x];
    }
    __syncthreads();
    int s = blockIdx.x*256 + threadIdx.x;
    float acc1[64];
    gather_conv1(s, idx, locF, nlocF, featT, sbuf, acc1);
    __syncthreads();
    for (int t = threadIdx.x; t < 64*64; t += 256){
        int c = t >> 6, o = t & 63;
        sbuf[c*64 + o] = W2[o*64 + c];
    }
    __syncthreads();
    float acc2[64];
    #pragma unroll
    for (int o = 0; o < 64; ++o) acc2[o] = 0.0f;
    #pragma unroll
    for (int c = 0; c < 64; ++c){
        float v = fmaxf(fmaf(acc1[c], sS1[c], sT1[c]), 0.0f);
        const float* wc = &sbuf[c*64];
        #pragma unroll
        for (int o = 0; o < 64; ++o) acc2[o] = fmaf(wc[o], v, acc2[o]);
    }
    __syncthreads();
    for (int t = threadIdx.x; t < 64*128; t += 256){
        int c = t >> 7, o = t & 127;
        sbuf[c*128 + o] = W3[o*64 + c];
    }
    __syncthreads();
    float acc3[128];
    #pragma unroll
    for (int o = 0; o < 128; ++o) acc3[o] = 0.0f;
    #pragma unroll
    for (int c = 0; c < 64; ++c){
        float v = fmaxf(fmaf(acc2[c], sS2[c], sT2[c]), 0.0f);
        const float* wc = &sbuf[c*128];
        #pragma unroll
        for (int o = 0; o < 128; ++o) acc3[o] = fmaf(wc[o], v, acc3[o]);
    }
    epilogue128(acc3, s, gmax, gmin, gsum, gsq, ldsS, ldsQ);
}

// ---------------------------------------------------------------------------
extern "C" void kernel_launch(void* const* d_in, const int* in_sizes, int n_in,
                              void* d_out, int out_size, void* d_ws, size_t ws_size,
                              hipStream_t stream){
    const float* loc  = (const float*)d_in[0];
    const float* nloc = (const float*)d_in[1];
    const float* feat = (const float*)d_in[2];
    const float* W1   = (const float*)d_in[3];
    const float* g1   = (const float*)d_in[4];
    const float* b1   = (const float*)d_in[5];
    const float* W2   = (const float*)d_in[6];
    const float* g2   = (const float*)d_in[7];
    const float* b2   = (const float*)d_in[8];
    const float* W3   = (const float*)d_in[9];
    const float* g3   = (const float*)d_in[10];
    const float* b3   = (const float*)d_in[11];
    float* out = (float*)d_out;

    char* ws = (char*)d_ws;
    float* stats = (float*)ws;                       // 512 f @ 0
    float* prm1  = (float*)(ws + 2048);              // 128 f
    float* prm2  = (float*)(ws + 2048 + 512);        // 128 f
    float* prm3  = (float*)(ws + 2048 + 1024);       // 256 f -> ends 4096
    int*   idx   = (int*)(ws + 4096);                // 2 MB -> ends 2101248
    float* gmax  = (float*)(ws + 2101248);           // 8 MB [128][BM]
    float* gmin  = (float*)(ws + 10489856);          // 8 MB
    float* featT = (float*)(ws + 18878464);          // 16 MB [B][N][64]
    u16*   y1    = (u16*)(ws + 35655680);            // 64 MB [64][NT]
    u16*   y2    = (u16*)(ws + 102764544);           // 64 MB

    const size_t FAST_NEED = 169873408ull;           // end of y2
    const bool fast = (ws_size >= FAST_NEED);

    hipMemsetAsync(stats, 0, 2048, stream);

    k_feat<<<dim3(N_/64, B_), 256, 0, stream>>>(feat, featT);
    k_knn<<<B_*M_, 256, 0, stream>>>(loc, nloc, idx);

    if (fast){
        k_conv1<<<NT/256, 256, 0, stream>>>(idx, loc, nloc, featT, W1, y1);
        k_stats<<<dim3(64, 32), 256, 0, stream>>>(y1, stats + 0, stats + 64);
        k_fold<<<1, 128, 0, stream>>>(stats + 0, stats + 64, g1, b1, prm1, 64);

        k_conv2<<<NT/256, 256, 0, stream>>>(y1, W2, prm1, y2);
        k_stats<<<dim3(64, 32), 256, 0, stream>>>(y2, stats + 128, stats + 192);
        k_fold<<<1, 128, 0, stream>>>(stats + 128, stats + 192, g2, b2, prm2, 64);

        k_conv3mm<<<NT/256, 256, 0, stream>>>(y2, W3, prm2, stats + 256, stats + 384, gmax, gmin);
        k_fold<<<1, 128, 0, stream>>>(stats + 256, stats + 384, g3, b3, prm3, 128);
    } else {
        k_q1<<<NT/256, 256, 0, stream>>>(idx, loc, nloc, featT, W1, stats + 0, stats + 64);
        k_fold<<<1, 128, 0, stream>>>(stats + 0, stats + 64, g1, b1, prm1, 64);

        k_q2<<<NT/256, 256, 0, stream>>>(idx, loc, nloc, featT, W1, W2, prm1, stats + 128, stats + 192);
        k_fold<<<1, 128, 0, stream>>>(stats + 128, stats + 192, g2, b2, prm2, 64);

        k_q3<<<NT/256, 256, 0, stream>>>(idx, loc, nloc, featT, W1, W2, W3, prm1, prm2,
                                         stats + 256, stats + 384, gmax, gmin);
        k_fold<<<1, 128, 0, stream>>>(stats + 256, stats + 384, g3, b3, prm3, 128);
    }

    k_final<<<dim3(M_/256, B_*128), 256, 0, stream>>>(gmax, gmin, prm3, out);
}

// Round 7
// 791.409 us; speedup vs baseline: 1.3605x; 1.3605x over previous
//
#include <hip/hip_runtime.h>
#include <stdint.h>

// Problem constants
#define B_   16
#define N_   4096
#define M_   1024
#define NT   (B_*M_*32)      // 524288 samples
#define BM   (B_*M_)         // 16384 (b,m) groups

typedef unsigned short u16;
typedef unsigned long long u64;

__device__ __forceinline__ float bf2f(u16 u){
    return __uint_as_float(((unsigned int)u) << 16);
}
__device__ __forceinline__ u16 f2bf(float f){
    unsigned int u = __float_as_uint(f);
    return (u16)((u + 0x7FFFu + ((u >> 16) & 1u)) >> 16);
}
__device__ __forceinline__ u64 umin64(u64 a, u64 b){ return a < b ? a : b; }

// ---------------------------------------------------------------------------
// features [B][64][N] f32 -> featT [B][N][64] f32
// ---------------------------------------------------------------------------
__global__ __launch_bounds__(256) void k_feat(const float* __restrict__ feat,
                                              float* __restrict__ featT){
    __shared__ float tile[64][65];
    int b  = blockIdx.y;
    int n0 = blockIdx.x * 64;
    for (int t = threadIdx.x; t < 4096; t += 256){
        int c = t >> 6, n = t & 63;
        tile[c][n] = feat[((size_t)(b*64 + c))*N_ + n0 + n];
    }
    __syncthreads();
    for (int t = threadIdx.x; t < 4096; t += 256){
        int n = t >> 6, c = t & 63;
        featT[((size_t)(b*N_) + n0 + n)*64 + c] = tile[c][n];
    }
}

// ---------------------------------------------------------------------------
// exact KNN (32 smallest of 4096) by iterative min-extraction on u64 keys
// ---------------------------------------------------------------------------
__global__ __launch_bounds__(256) void k_knn(const float* __restrict__ locF,
                                             const float* __restrict__ nlocF,
                                             int* __restrict__ idxOut){
    const int tid  = threadIdx.x;
    const int lane = tid & 63, wave = tid >> 6;
    const int q    = blockIdx.x;
    const int b    = q >> 10, m = q & 1023;

    float qx = nlocF[(size_t)(b*M_ + m)*3 + 0];
    float qy = nlocF[(size_t)(b*M_ + m)*3 + 1];
    float qz = nlocF[(size_t)(b*M_ + m)*3 + 2];
    float y2 = __fadd_rn(__fadd_rn(__fmul_rn(qx,qx), __fmul_rn(qy,qy)), __fmul_rn(qz,qz));

    u64 key[16];
    const float* lb = locF + (size_t)b*N_*3;
    #pragma unroll
    for (int i = 0; i < 16; ++i){
        int n = i*256 + tid;
        float lx = lb[n*3+0], ly = lb[n*3+1], lz = lb[n*3+2];
        float x2 = __fadd_rn(__fadd_rn(__fmul_rn(lx,lx), __fmul_rn(ly,ly)), __fmul_rn(lz,lz));
        float dt = __fadd_rn(__fadd_rn(__fmul_rn(qx,lx), __fmul_rn(qy,ly)), __fmul_rn(qz,lz));
        float d2 = __fsub_rn(__fadd_rn(y2, x2), __fmul_rn(2.0f, dt));
        d2 = fmaxf(d2, 0.0f);
        key[i] = (((u64)__float_as_uint(d2)) << 32) | (unsigned int)n;
    }

    u64 myMin = key[0];
    #pragma unroll
    for (int i = 1; i < 16; ++i) myMin = umin64(myMin, key[i]);

    __shared__ u64 wmin[4];

    for (int r = 0; r < 32; ++r){
        u64 v = myMin;
        #pragma unroll
        for (int st = 32; st >= 1; st >>= 1)
            v = umin64(v, __shfl_down(v, st, 64));
        if (lane == 0) wmin[wave] = v;
        __syncthreads();
        u64 gbest = umin64(umin64(wmin[0], wmin[1]), umin64(wmin[2], wmin[3]));
        if (tid == 0) idxOut[(size_t)q*32 + r] = (int)(gbest & 0xFFFFFFFFu);
        if (myMin == gbest){
            u64 nm = ~0ull;
            #pragma unroll
            for (int i = 0; i < 16; ++i){
                if (key[i] == gbest) key[i] = ~0ull;
                nm = umin64(nm, key[i]);
            }
            myMin = nm;
        }
        __syncthreads();
    }
}

// ---------------------------------------------------------------------------
// conv1 tiled: thread = (o-block 16, s-block 4); gather staged via LDS.
// block covers 256 samples. acc[16][4] in regs.
// ---------------------------------------------------------------------------
__global__ __launch_bounds__(256) void k_conv1t(const int* __restrict__ idx,
                                                const float* __restrict__ locF,
                                                const float* __restrict__ nlocF,
                                                const float* __restrict__ featT,
                                                const float* __restrict__ W1,
                                                u16* __restrict__ y1){
    __shared__ float Wl[67*64];     // [c][o]
    __shared__ float At[16*256];    // [c_local][s_local]
    const int t  = threadIdx.x;
    const int s0 = blockIdx.x * 256;
    for (int i = t; i < 67*64; i += 256){
        int c = i >> 6, o = i & 63;
        Wl[i] = W1[o*67 + c];
    }
    __syncthreads();

    const int ob = t >> 6;          // 0..3
    const int sb = t & 63;          // 0..63
    const int o0 = ob*16;
    const int b  = s0 >> 15;
    float acc[16][4];

    // init with rel-xyz (channels 0..2)
    {
        int4 nn = *(const int4*)&idx[s0 + sb*4];
        int ns[4] = {nn.x, nn.y, nn.z, nn.w};
        int m = ((s0 + sb*4) >> 5) & 1023;
        float qx = nlocF[(size_t)(b*M_ + m)*3 + 0];
        float qy = nlocF[(size_t)(b*M_ + m)*3 + 1];
        float qz = nlocF[(size_t)(b*M_ + m)*3 + 2];
        float r0[4], r1[4], r2[4];
        #pragma unroll
        for (int j = 0; j < 4; ++j){
            int n = ns[j]; if ((unsigned)n >= N_) n = 0;
            const float* lp = &locF[(size_t)(b*N_ + n)*3];
            r0[j] = lp[0] - qx; r1[j] = lp[1] - qy; r2[j] = lp[2] - qz;
        }
        #pragma unroll
        for (int i = 0; i < 16; ++i){
            float w0 = Wl[o0 + i], w1 = Wl[64 + o0 + i], w2 = Wl[128 + o0 + i];
            #pragma unroll
            for (int j = 0; j < 4; ++j)
                acc[i][j] = fmaf(w2, r2[j], fmaf(w1, r1[j], w0*r0[j]));
        }
    }

    for (int pass = 0; pass < 4; ++pass){
        __syncthreads();
        // stage: thread t gathers featT row of sample t, cols pass*16..+15
        {
            int n = idx[s0 + t]; if ((unsigned)n >= N_) n = 0;
            const float4* fr = (const float4*)&featT[((size_t)(b*N_) + n)*64 + pass*16];
            #pragma unroll
            for (int q = 0; q < 4; ++q){
                float4 f = fr[q];
                At[(q*4+0)*256 + t] = f.x;
                At[(q*4+1)*256 + t] = f.y;
                At[(q*4+2)*256 + t] = f.z;
                At[(q*4+3)*256 + t] = f.w;
            }
        }
        __syncthreads();
        const float4* Wrow = (const float4*)&Wl[(3 + pass*16)*64];
        #pragma unroll
        for (int c = 0; c < 16; ++c){
            float4 a = *(const float4*)&At[c*256 + sb*4];
            float av[4] = {a.x, a.y, a.z, a.w};
            #pragma unroll
            for (int q = 0; q < 4; ++q){
                float4 w = Wrow[c*16 + ob*4 + q];
                float wv[4] = {w.x, w.y, w.z, w.w};
                #pragma unroll
                for (int r = 0; r < 4; ++r)
                    #pragma unroll
                    for (int j = 0; j < 4; ++j)
                        acc[q*4+r][j] = fmaf(wv[r], av[j], acc[q*4+r][j]);
            }
        }
    }
    #pragma unroll
    for (int i = 0; i < 16; ++i){
        ushort4 pk;
        pk.x = f2bf(acc[i][0]); pk.y = f2bf(acc[i][1]);
        pk.z = f2bf(acc[i][2]); pk.w = f2bf(acc[i][3]);
        *(ushort4*)&y1[(size_t)(o0+i)*NT + s0 + sb*4] = pk;
    }
}

// ---------------------------------------------------------------------------
// conv2 tiled: y2 = W2 · relu(y1*s+t).  thread = (o-block 16, s-block 4).
// ---------------------------------------------------------------------------
__global__ __launch_bounds__(256) void k_conv2t(const u16* __restrict__ yin,
                                                const float* __restrict__ W2,
                                                const float* __restrict__ prm,
                                                u16* __restrict__ yout){
    __shared__ float Wl[64*64];     // [c][o]
    __shared__ float At[16*256];
    __shared__ float sS[64], sT[64];
    const int t  = threadIdx.x;
    const int s0 = blockIdx.x * 256;
    for (int i = t; i < 64*64; i += 256){
        int c = i >> 6, o = i & 63;
        Wl[i] = W2[o*64 + c];
    }
    if (t < 64){ sS[t] = prm[t]; sT[t] = prm[64 + t]; }

    const int ob = t >> 6, sb = t & 63, o0 = ob*16;
    float acc[16][4];
    #pragma unroll
    for (int i = 0; i < 16; ++i)
        #pragma unroll
        for (int j = 0; j < 4; ++j) acc[i][j] = 0.0f;

    for (int pass = 0; pass < 4; ++pass){
        __syncthreads();
        #pragma unroll
        for (int rep = 0; rep < 2; ++rep){
            int v = rep*256 + t;
            int row = v >> 5, ch = v & 31;
            int c = pass*16 + row;
            uint4 pk = *(const uint4*)&yin[(size_t)c*NT + s0 + ch*8];
            float sc = sS[c], tt = sT[c];
            unsigned int w4[4] = {pk.x, pk.y, pk.z, pk.w};
            float f[8];
            #pragma unroll
            for (int q = 0; q < 4; ++q){
                f[2*q]   = fmaxf(fmaf(bf2f((u16)(w4[q] & 0xFFFF)), sc, tt), 0.0f);
                f[2*q+1] = fmaxf(fmaf(bf2f((u16)(w4[q] >> 16)),   sc, tt), 0.0f);
            }
            float4 f1 = {f[0], f[1], f[2], f[3]};
            float4 f2 = {f[4], f[5], f[6], f[7]};
            *(float4*)&At[row*256 + ch*8]     = f1;
            *(float4*)&At[row*256 + ch*8 + 4] = f2;
        }
        __syncthreads();
        const float4* Wrow = (const float4*)&Wl[(pass*16)*64];
        #pragma unroll
        for (int c = 0; c < 16; ++c){
            float4 a = *(const float4*)&At[c*256 + sb*4];
            float av[4] = {a.x, a.y, a.z, a.w};
            #pragma unroll
            for (int q = 0; q < 4; ++q){
                float4 w = Wrow[c*16 + ob*4 + q];
                float wv[4] = {w.x, w.y, w.z, w.w};
                #pragma unroll
                for (int r = 0; r < 4; ++r)
                    #pragma unroll
                    for (int j = 0; j < 4; ++j)
                        acc[q*4+r][j] = fmaf(wv[r], av[j], acc[q*4+r][j]);
            }
        }
    }
    #pragma unroll
    for (int i = 0; i < 16; ++i){
        ushort4 pk;
        pk.x = f2bf(acc[i][0]); pk.y = f2bf(acc[i][1]);
        pk.z = f2bf(acc[i][2]); pk.w = f2bf(acc[i][3]);
        *(ushort4*)&yout[(size_t)(o0+i)*NT + s0 + sb*4] = pk;
    }
}

// ---------------------------------------------------------------------------
// conv3 tiled + fused stats/minmax: thread = (group, 4-channel block), owns all
// 32 k of its group -> max/min/sum/sq purely in registers, zero shuffles.
// ---------------------------------------------------------------------------
__global__ __launch_bounds__(256) void k_conv3t(const u16* __restrict__ yin,
                                                const float* __restrict__ W3,
                                                const float* __restrict__ prm,
                                                float* __restrict__ gsum, float* __restrict__ gsq,
                                                float* __restrict__ gmax, float* __restrict__ gmin){
    __shared__ float Wl[64*128];    // [c][o]  32 KB
    __shared__ float At[16*256];    // 16 KB
    __shared__ float sS[64], sT[64];
    __shared__ float sSum[128], sSq[128];
    const int t  = threadIdx.x;
    const int s0 = blockIdx.x * 256;
    for (int i = t; i < 64*128; i += 256){
        int c = i >> 7, o = i & 127;
        Wl[i] = W3[o*64 + c];
    }
    if (t < 64){ sS[t] = prm[t]; sT[t] = prm[64 + t]; }
    if (t < 128){ sSum[t] = 0.0f; sSq[t] = 0.0f; }

    const int g  = t >> 5;          // 0..7 (group within block)
    const int oq = t & 31;          // 0..31
    const int o0 = oq*4;
    float acc[4][32];
    #pragma unroll
    for (int r = 0; r < 4; ++r)
        #pragma unroll
        for (int k = 0; k < 32; ++k) acc[r][k] = 0.0f;

    for (int pass = 0; pass < 4; ++pass){
        __syncthreads();
        #pragma unroll
        for (int rep = 0; rep < 2; ++rep){
            int v = rep*256 + t;
            int row = v >> 5, ch = v & 31;
            int c = pass*16 + row;
            uint4 pk = *(const uint4*)&yin[(size_t)c*NT + s0 + ch*8];
            float sc = sS[c], tt = sT[c];
            unsigned int w4[4] = {pk.x, pk.y, pk.z, pk.w};
            float f[8];
            #pragma unroll
            for (int q = 0; q < 4; ++q){
                f[2*q]   = fmaxf(fmaf(bf2f((u16)(w4[q] & 0xFFFF)), sc, tt), 0.0f);
                f[2*q+1] = fmaxf(fmaf(bf2f((u16)(w4[q] >> 16)),   sc, tt), 0.0f);
            }
            float4 f1 = {f[0], f[1], f[2], f[3]};
            float4 f2 = {f[4], f[5], f[6], f[7]};
            *(float4*)&At[row*256 + ch*8]     = f1;
            *(float4*)&At[row*256 + ch*8 + 4] = f2;
        }
        __syncthreads();
        #pragma unroll
        for (int c = 0; c < 16; ++c){
            float4 w = *(const float4*)&Wl[(pass*16 + c)*128 + o0];
            float wv[4] = {w.x, w.y, w.z, w.w};
            const float* ap = &At[c*256 + g*32];
            #pragma unroll
            for (int k4 = 0; k4 < 8; ++k4){
                float4 a = *(const float4*)&ap[k4*4];
                float av[4] = {a.x, a.y, a.z, a.w};
                #pragma unroll
                for (int r = 0; r < 4; ++r)
                    #pragma unroll
                    for (int j = 0; j < 4; ++j)
                        acc[r][k4*4+j] = fmaf(wv[r], av[j], acc[r][k4*4+j]);
            }
        }
    }
    // epilogue: in-register reductions over k
    const int gg = blockIdx.x*8 + g;
    #pragma unroll
    for (int r = 0; r < 4; ++r){
        float mx = acc[r][0], mn = acc[r][0], sm = acc[r][0];
        float sq = acc[r][0]*acc[r][0];
        #pragma unroll
        for (int k = 1; k < 32; ++k){
            float v = acc[r][k];
            mx = fmaxf(mx, v); mn = fminf(mn, v);
            sm += v; sq = fmaf(v, v, sq);
        }
        gmax[(size_t)(o0+r)*BM + gg] = mx;
        gmin[(size_t)(o0+r)*BM + gg] = mn;
        atomicAdd(&sSum[o0+r], sm);
        atomicAdd(&sSq[o0+r], sq);
    }
    __syncthreads();
    if (t < 128){
        atomicAdd(&gsum[t], sSum[t]);
        atomicAdd(&gsq[t],  sSq[t]);
    }
}

// ---------------------------------------------------------------------------
// per-channel sum/sumsq over stored y (bf16 channel-major), vectorized
// ---------------------------------------------------------------------------
__global__ __launch_bounds__(256) void k_stats(const u16* __restrict__ y,
                                               float* __restrict__ sum,
                                               float* __restrict__ sumsq){
    int c = blockIdx.x, chunk = blockIdx.y;
    size_t base = (size_t)c*NT + (size_t)chunk*16384;
    const uint2* p = (const uint2*)(y + base);
    float s = 0.0f, qq = 0.0f;
    for (int i = threadIdx.x; i < 4096; i += 256){
        uint2 v = p[i];
        float v0 = bf2f((u16)(v.x & 0xFFFF)), v1 = bf2f((u16)(v.x >> 16));
        float v2 = bf2f((u16)(v.y & 0xFFFF)), v3 = bf2f((u16)(v.y >> 16));
        s += v0 + v1 + v2 + v3;
        qq = fmaf(v0, v0, qq); qq = fmaf(v1, v1, qq);
        qq = fmaf(v2, v2, qq); qq = fmaf(v3, v3, qq);
    }
    #pragma unroll
    for (int off = 32; off > 0; off >>= 1){
        s  += __shfl_down(s,  off, 64);
        qq += __shfl_down(qq, off, 64);
    }
    __shared__ float aS[4], aQ[4];
    int wave = threadIdx.x >> 6, lane = threadIdx.x & 63;
    if (lane == 0){ aS[wave] = s; aQ[wave] = qq; }
    __syncthreads();
    if (threadIdx.x == 0){
        atomicAdd(&sum[c],   aS[0] + aS[1] + aS[2] + aS[3]);
        atomicAdd(&sumsq[c], aQ[0] + aQ[1] + aQ[2] + aQ[3]);
    }
}

// fold BN into affine: s = g*rsqrt(var+eps), t = b - mu*s
__global__ void k_fold(const float* __restrict__ sum, const float* __restrict__ sumsq,
                       const float* __restrict__ gW, const float* __restrict__ bW,
                       float* __restrict__ prm, int C){
    int c = threadIdx.x;
    if (c < C){
        const float inv = 1.0f / (float)NT;
        float mu  = sum[c] * inv;
        float var = sumsq[c] * inv - mu*mu;
        float sc  = gW[c] / sqrtf(var + 1e-5f);
        prm[c]     = sc;
        prm[C + c] = bW[c] - mu*sc;
    }
}

// out[b][o][m] = ReLU(s * (s>=0 ? gmax : gmin) + t)   -- f32 output
__global__ __launch_bounds__(256) void k_final(const float* __restrict__ gmax,
                                               const float* __restrict__ gmin,
                                               const float* __restrict__ prm,
                                               float* __restrict__ out){
    int bo = blockIdx.y;
    int b = bo >> 7, o = bo & 127;
    int m = blockIdx.x*256 + threadIdx.x;
    float sc = prm[o], tt = prm[128 + o];
    size_t i = (size_t)o*BM + b*M_ + m;
    float v = (sc >= 0.0f) ? gmax[i] : gmin[i];
    out[((size_t)(b*128 + o))*M_ + m] = fmaxf(fmaf(v, sc, tt), 0.0f);
}

// ---------------------------------------------------------------------------
extern "C" void kernel_launch(void* const* d_in, const int* in_sizes, int n_in,
                              void* d_out, int out_size, void* d_ws, size_t ws_size,
                              hipStream_t stream){
    const float* loc  = (const float*)d_in[0];
    const float* nloc = (const float*)d_in[1];
    const float* feat = (const float*)d_in[2];
    const float* W1   = (const float*)d_in[3];
    const float* g1   = (const float*)d_in[4];
    const float* b1   = (const float*)d_in[5];
    const float* W2   = (const float*)d_in[6];
    const float* g2   = (const float*)d_in[7];
    const float* b2   = (const float*)d_in[8];
    const float* W3   = (const float*)d_in[9];
    const float* g3   = (const float*)d_in[10];
    const float* b3   = (const float*)d_in[11];
    float* out = (float*)d_out;

    char* ws = (char*)d_ws;
    float* stats = (float*)ws;                       // 512 f @ 0
    float* prm1  = (float*)(ws + 2048);              // 128 f
    float* prm2  = (float*)(ws + 2048 + 512);        // 128 f
    float* prm3  = (float*)(ws + 2048 + 1024);       // 256 f -> ends 4096
    int*   idx   = (int*)(ws + 4096);                // 2 MB
    float* gmax  = (float*)(ws + 2101248);           // 8 MB [128][BM]
    float* gmin  = (float*)(ws + 10489856);          // 8 MB
    float* featT = (float*)(ws + 18878464);          // 16 MB [B][N][64]
    u16*   y1    = (u16*)(ws + 35655680);            // 64 MB [64][NT]
    u16*   y2    = (u16*)(ws + 102764544);           // 64 MB  (ws >= 170 MB proven in R6)

    hipMemsetAsync(stats, 0, 2048, stream);

    k_feat<<<dim3(N_/64, B_), 256, 0, stream>>>(feat, featT);
    k_knn<<<B_*M_, 256, 0, stream>>>(loc, nloc, idx);

    k_conv1t<<<NT/256, 256, 0, stream>>>(idx, loc, nloc, featT, W1, y1);
    k_stats<<<dim3(64, 32), 256, 0, stream>>>(y1, stats + 0, stats + 64);
    k_fold<<<1, 128, 0, stream>>>(stats + 0, stats + 64, g1, b1, prm1, 64);

    k_conv2t<<<NT/256, 256, 0, stream>>>(y1, W2, prm1, y2);
    k_stats<<<dim3(64, 32), 256, 0, stream>>>(y2, stats + 128, stats + 192);
    k_fold<<<1, 128, 0, stream>>>(stats + 128, stats + 192, g2, b2, prm2, 64);

    k_conv3t<<<NT/256, 256, 0, stream>>>(y2, W3, prm2, stats + 256, stats + 384, gmax, gmin);
    k_fold<<<1, 128, 0, stream>>>(stats + 256, stats + 384, g3, b3, prm3, 128);

    k_final<<<dim3(M_/256, B_*128), 256, 0, stream>>>(gmax, gmin, prm3, out);
}

// Round 8
// 680.632 us; speedup vs baseline: 1.5820x; 1.1628x over previous
//
#include <hip/hip_runtime.h>
#include <stdint.h>

// Problem constants
#define B_   16
#define N_   4096
#define M_   1024
#define NT   (B_*M_*32)      // 524288 samples
#define BM   (B_*M_)         // 16384 (b,m) groups

typedef unsigned short u16;
typedef unsigned long long u64;

__device__ __forceinline__ float bf2f(u16 u){
    return __uint_as_float(((unsigned int)u) << 16);
}
__device__ __forceinline__ u16 f2bf(float f){
    unsigned int u = __float_as_uint(f);
    return (u16)((u + 0x7FFFu + ((u >> 16) & 1u)) >> 16);
}

// ---------------------------------------------------------------------------
// features [B][64][N] f32 -> featT [B][N][64] f32
// ---------------------------------------------------------------------------
__global__ __launch_bounds__(256) void k_feat(const float* __restrict__ feat,
                                              float* __restrict__ featT){
    __shared__ float tile[64][65];
    int b  = blockIdx.y;
    int n0 = blockIdx.x * 64;
    for (int t = threadIdx.x; t < 4096; t += 256){
        int c = t >> 6, n = t & 63;
        tile[c][n] = feat[((size_t)(b*64 + c))*N_ + n0 + n];
    }
    __syncthreads();
    for (int t = threadIdx.x; t < 4096; t += 256){
        int n = t >> 6, c = t & 63;
        featT[((size_t)(b*N_) + n0 + n)*64 + c] = tile[c][n];
    }
}

// ---------------------------------------------------------------------------
// exact KNN (32 smallest of 4096): block-cooperative nibble radix-select on
// u32 distance bits + lowest-index tie resolution (set-equal to lax.top_k;
// downstream BN/max is order-invariant). Early exit when the rank bucket is
// fully consumed (cnt == R).
// ---------------------------------------------------------------------------
__global__ __launch_bounds__(256) void k_knn(const float* __restrict__ locF,
                                             const float* __restrict__ nlocF,
                                             int* __restrict__ idxOut){
    const int tid  = threadIdx.x;
    const int lane = tid & 63, wave = tid >> 6;
    const int q    = blockIdx.x;
    const int b    = q >> 10, m = q & 1023;

    float qx = nlocF[(size_t)(b*M_ + m)*3 + 0];
    float qy = nlocF[(size_t)(b*M_ + m)*3 + 1];
    float qz = nlocF[(size_t)(b*M_ + m)*3 + 2];
    float y2 = __fadd_rn(__fadd_rn(__fmul_rn(qx,qx), __fmul_rn(qy,qy)), __fmul_rn(qz,qz));

    unsigned int key[16];
    const float* lb = locF + (size_t)b*N_*3;
    #pragma unroll
    for (int i = 0; i < 16; ++i){
        int n = i*256 + tid;
        float lx = lb[n*3+0], ly = lb[n*3+1], lz = lb[n*3+2];
        float x2 = __fadd_rn(__fadd_rn(__fmul_rn(lx,lx), __fmul_rn(ly,ly)), __fmul_rn(lz,lz));
        float dt = __fadd_rn(__fadd_rn(__fmul_rn(qx,lx), __fmul_rn(qy,ly)), __fmul_rn(qz,lz));
        float d2 = __fsub_rn(__fadd_rn(y2, x2), __fmul_rn(2.0f, dt));
        d2 = fmaxf(d2, 0.0f);                  // uint order == float order
        key[i] = __float_as_uint(d2);
    }

    __shared__ u64 hWave[4][4];        // per-wave packed histograms
    __shared__ int sOutI[32];
    __shared__ int sTies[128];
    __shared__ int cLess, cTie;

    unsigned int prefix = 0;
    unsigned int pivot  = 0;
    int R = 32;
    bool found = false;

    for (int p = 0; p < 8; ++p){
        const int shift = 28 - 4*p;
        // local packed histogram: 4 u64, 16-bit fields, 4 buckets each
        u64 h0 = 0, h1 = 0, h2 = 0, h3 = 0;
        #pragma unroll
        for (int i = 0; i < 16; ++i){
            unsigned int k = key[i];
            bool act = (p == 0) || ((k >> (shift+4)) == (prefix >> (shift+4)));
            unsigned int d = (k >> shift) & 15u;
            u64 inc = act ? (1ull << ((d & 3u)*16)) : 0ull;
            unsigned int hi = d >> 2;
            h0 += (hi == 0u) ? inc : 0ull;
            h1 += (hi == 1u) ? inc : 0ull;
            h2 += (hi == 2u) ? inc : 0ull;
            h3 += (hi == 3u) ? inc : 0ull;
        }
        // wave butterfly reduce (all lanes end with wave total)
        #pragma unroll
        for (int st = 1; st < 64; st <<= 1){
            h0 += __shfl_xor(h0, st, 64);
            h1 += __shfl_xor(h1, st, 64);
            h2 += __shfl_xor(h2, st, 64);
            h3 += __shfl_xor(h3, st, 64);
        }
        if (lane == 0){
            hWave[wave][0] = h0; hWave[wave][1] = h1;
            hWave[wave][2] = h2; hWave[wave][3] = h3;
        }
        __syncthreads();
        u64 H[4];
        #pragma unroll
        for (int j = 0; j < 4; ++j)
            H[j] = hWave[0][j] + hWave[1][j] + hWave[2][j] + hWave[3][j];
        __syncthreads();                      // hWave reusable next pass

        // uniform scan of 16 buckets
        int cum = 0, dsel = 0, cnt = 0, below = 0, got = 0;
        #pragma unroll
        for (int j = 0; j < 16; ++j){
            int c = (int)((H[j >> 2] >> ((j & 3)*16)) & 0xFFFFull);
            if (!got && (cum + c) >= R){ dsel = j; cnt = c; below = cum; got = 1; }
            cum += c;
        }
        prefix |= ((unsigned int)dsel) << shift;
        R -= below;
        if (cnt == R){                        // whole bucket selected
            pivot = prefix | (shift ? ((1u << shift) - 1u) : 0u);
            found = true;
            break;                            // uniform across block
        }
    }
    if (!found) pivot = prefix;               // full 32-bit pivot after 8 passes

    if (tid == 0){ cLess = 0; cTie = 0; }
    __syncthreads();
    #pragma unroll
    for (int i = 0; i < 16; ++i){
        int n = i*256 + tid;
        if (key[i] < pivot){
            int pos = atomicAdd(&cLess, 1);
            sOutI[pos] = n;                   // L <= 32 guaranteed
        } else if (key[i] == pivot){
            int pos = atomicAdd(&cTie, 1);
            if (pos < 128) sTies[pos] = n;
        }
    }
    __syncthreads();
    if (tid == 0){
        int need = 32 - cLess;
        int ct = cTie; if (ct > 128) ct = 128;
        for (int a = 0; a < need; ++a){       // smallest `need` indices among ties
            int bi = a;
            for (int c2 = a+1; c2 < ct; ++c2) if (sTies[c2] < sTies[bi]) bi = c2;
            int tmp = sTies[a]; sTies[a] = sTies[bi]; sTies[bi] = tmp;
            sOutI[cLess + a] = sTies[a];
        }
    }
    __syncthreads();
    if (tid < 32) idxOut[(size_t)q*32 + tid] = sOutI[tid];
}

// ---------------------------------------------------------------------------
// conv1 tiled: thread = (o-block 16, s-block 4); gather staged via LDS.
// ---------------------------------------------------------------------------
__global__ __launch_bounds__(256) void k_conv1t(const int* __restrict__ idx,
                                                const float* __restrict__ locF,
                                                const float* __restrict__ nlocF,
                                                const float* __restrict__ featT,
                                                const float* __restrict__ W1,
                                                u16* __restrict__ y1){
    __shared__ float Wl[67*64];     // [c][o]
    __shared__ float At[16*256];    // [c_local][s_local]
    const int t  = threadIdx.x;
    const int s0 = blockIdx.x * 256;
    for (int i = t; i < 67*64; i += 256){
        int c = i >> 6, o = i & 63;
        Wl[i] = W1[o*67 + c];
    }
    __syncthreads();

    const int ob = t >> 6;          // 0..3
    const int sb = t & 63;          // 0..63
    const int o0 = ob*16;
    const int b  = s0 >> 15;
    float acc[16][4];

    {
        int4 nn = *(const int4*)&idx[s0 + sb*4];
        int ns[4] = {nn.x, nn.y, nn.z, nn.w};
        int m = ((s0 + sb*4) >> 5) & 1023;
        float qx = nlocF[(size_t)(b*M_ + m)*3 + 0];
        float qy = nlocF[(size_t)(b*M_ + m)*3 + 1];
        float qz = nlocF[(size_t)(b*M_ + m)*3 + 2];
        float r0[4], r1[4], r2[4];
        #pragma unroll
        for (int j = 0; j < 4; ++j){
            int n = ns[j]; if ((unsigned)n >= N_) n = 0;
            const float* lp = &locF[(size_t)(b*N_ + n)*3];
            r0[j] = lp[0] - qx; r1[j] = lp[1] - qy; r2[j] = lp[2] - qz;
        }
        #pragma unroll
        for (int i = 0; i < 16; ++i){
            float w0 = Wl[o0 + i], w1 = Wl[64 + o0 + i], w2 = Wl[128 + o0 + i];
            #pragma unroll
            for (int j = 0; j < 4; ++j)
                acc[i][j] = fmaf(w2, r2[j], fmaf(w1, r1[j], w0*r0[j]));
        }
    }

    for (int pass = 0; pass < 4; ++pass){
        __syncthreads();
        {
            int n = idx[s0 + t]; if ((unsigned)n >= N_) n = 0;
            const float4* fr = (const float4*)&featT[((size_t)(b*N_) + n)*64 + pass*16];
            #pragma unroll
            for (int q = 0; q < 4; ++q){
                float4 f = fr[q];
                At[(q*4+0)*256 + t] = f.x;
                At[(q*4+1)*256 + t] = f.y;
                At[(q*4+2)*256 + t] = f.z;
                At[(q*4+3)*256 + t] = f.w;
            }
        }
        __syncthreads();
        const float4* Wrow = (const float4*)&Wl[(3 + pass*16)*64];
        #pragma unroll
        for (int c = 0; c < 16; ++c){
            float4 a = *(const float4*)&At[c*256 + sb*4];
            float av[4] = {a.x, a.y, a.z, a.w};
            #pragma unroll
            for (int q = 0; q < 4; ++q){
                float4 w = Wrow[c*16 + ob*4 + q];
                float wv[4] = {w.x, w.y, w.z, w.w};
                #pragma unroll
                for (int r = 0; r < 4; ++r)
                    #pragma unroll
                    for (int j = 0; j < 4; ++j)
                        acc[q*4+r][j] = fmaf(wv[r], av[j], acc[q*4+r][j]);
            }
        }
    }
    #pragma unroll
    for (int i = 0; i < 16; ++i){
        ushort4 pk;
        pk.x = f2bf(acc[i][0]); pk.y = f2bf(acc[i][1]);
        pk.z = f2bf(acc[i][2]); pk.w = f2bf(acc[i][3]);
        *(ushort4*)&y1[(size_t)(o0+i)*NT + s0 + sb*4] = pk;
    }
}

// ---------------------------------------------------------------------------
// conv2 tiled
// ---------------------------------------------------------------------------
__global__ __launch_bounds__(256) void k_conv2t(const u16* __restrict__ yin,
                                                const float* __restrict__ W2,
                                                const float* __restrict__ prm,
                                                u16* __restrict__ yout){
    __shared__ float Wl[64*64];     // [c][o]
    __shared__ float At[16*256];
    __shared__ float sS[64], sT[64];
    const int t  = threadIdx.x;
    const int s0 = blockIdx.x * 256;
    for (int i = t; i < 64*64; i += 256){
        int c = i >> 6, o = i & 63;
        Wl[i] = W2[o*64 + c];
    }
    if (t < 64){ sS[t] = prm[t]; sT[t] = prm[64 + t]; }

    const int ob = t >> 6, sb = t & 63, o0 = ob*16;
    float acc[16][4];
    #pragma unroll
    for (int i = 0; i < 16; ++i)
        #pragma unroll
        for (int j = 0; j < 4; ++j) acc[i][j] = 0.0f;

    for (int pass = 0; pass < 4; ++pass){
        __syncthreads();
        #pragma unroll
        for (int rep = 0; rep < 2; ++rep){
            int v = rep*256 + t;
            int row = v >> 5, ch = v & 31;
            int c = pass*16 + row;
            uint4 pk = *(const uint4*)&yin[(size_t)c*NT + s0 + ch*8];
            float sc = sS[c], tt = sT[c];
            unsigned int w4[4] = {pk.x, pk.y, pk.z, pk.w};
            float f[8];
            #pragma unroll
            for (int q = 0; q < 4; ++q){
                f[2*q]   = fmaxf(fmaf(bf2f((u16)(w4[q] & 0xFFFF)), sc, tt), 0.0f);
                f[2*q+1] = fmaxf(fmaf(bf2f((u16)(w4[q] >> 16)),   sc, tt), 0.0f);
            }
            float4 f1 = {f[0], f[1], f[2], f[3]};
            float4 f2 = {f[4], f[5], f[6], f[7]};
            *(float4*)&At[row*256 + ch*8]     = f1;
            *(float4*)&At[row*256 + ch*8 + 4] = f2;
        }
        __syncthreads();
        const float4* Wrow = (const float4*)&Wl[(pass*16)*64];
        #pragma unroll
        for (int c = 0; c < 16; ++c){
            float4 a = *(const float4*)&At[c*256 + sb*4];
            float av[4] = {a.x, a.y, a.z, a.w};
            #pragma unroll
            for (int q = 0; q < 4; ++q){
                float4 w = Wrow[c*16 + ob*4 + q];
                float wv[4] = {w.x, w.y, w.z, w.w};
                #pragma unroll
                for (int r = 0; r < 4; ++r)
                    #pragma unroll
                    for (int j = 0; j < 4; ++j)
                        acc[q*4+r][j] = fmaf(wv[r], av[j], acc[q*4+r][j]);
            }
        }
    }
    #pragma unroll
    for (int i = 0; i < 16; ++i){
        ushort4 pk;
        pk.x = f2bf(acc[i][0]); pk.y = f2bf(acc[i][1]);
        pk.z = f2bf(acc[i][2]); pk.w = f2bf(acc[i][3]);
        *(ushort4*)&yout[(size_t)(o0+i)*NT + s0 + sb*4] = pk;
    }
}

// ---------------------------------------------------------------------------
// conv3 tiled + fused stats/minmax (in-register k reductions)
// ---------------------------------------------------------------------------
__global__ __launch_bounds__(256) void k_conv3t(const u16* __restrict__ yin,
                                                const float* __restrict__ W3,
                                                const float* __restrict__ prm,
                                                float* __restrict__ gsum, float* __restrict__ gsq,
                                                float* __restrict__ gmax, float* __restrict__ gmin){
    __shared__ float Wl[64*128];    // [c][o]
    __shared__ float At[16*256];
    __shared__ float sS[64], sT[64];
    __shared__ float sSum[128], sSq[128];
    const int t  = threadIdx.x;
    const int s0 = blockIdx.x * 256;
    for (int i = t; i < 64*128; i += 256){
        int c = i >> 7, o = i & 127;
        Wl[i] = W3[o*64 + c];
    }
    if (t < 64){ sS[t] = prm[t]; sT[t] = prm[64 + t]; }
    if (t < 128){ sSum[t] = 0.0f; sSq[t] = 0.0f; }

    const int g  = t >> 5;
    const int oq = t & 31;
    const int o0 = oq*4;
    float acc[4][32];
    #pragma unroll
    for (int r = 0; r < 4; ++r)
        #pragma unroll
        for (int k = 0; k < 32; ++k) acc[r][k] = 0.0f;

    for (int pass = 0; pass < 4; ++pass){
        __syncthreads();
        #pragma unroll
        for (int rep = 0; rep < 2; ++rep){
            int v = rep*256 + t;
            int row = v >> 5, ch = v & 31;
            int c = pass*16 + row;
            uint4 pk = *(const uint4*)&yin[(size_t)c*NT + s0 + ch*8];
            float sc = sS[c], tt = sT[c];
            unsigned int w4[4] = {pk.x, pk.y, pk.z, pk.w};
            float f[8];
            #pragma unroll
            for (int q = 0; q < 4; ++q){
                f[2*q]   = fmaxf(fmaf(bf2f((u16)(w4[q] & 0xFFFF)), sc, tt), 0.0f);
                f[2*q+1] = fmaxf(fmaf(bf2f((u16)(w4[q] >> 16)),   sc, tt), 0.0f);
            }
            float4 f1 = {f[0], f[1], f[2], f[3]};
            float4 f2 = {f[4], f[5], f[6], f[7]};
            *(float4*)&At[row*256 + ch*8]     = f1;
            *(float4*)&At[row*256 + ch*8 + 4] = f2;
        }
        __syncthreads();
        #pragma unroll
        for (int c = 0; c < 16; ++c){
            float4 w = *(const float4*)&Wl[(pass*16 + c)*128 + o0];
            float wv[4] = {w.x, w.y, w.z, w.w};
            const float* ap = &At[c*256 + g*32];
            #pragma unroll
            for (int k4 = 0; k4 < 8; ++k4){
                float4 a = *(const float4*)&ap[k4*4];
                float av[4] = {a.x, a.y, a.z, a.w};
                #pragma unroll
                for (int r = 0; r < 4; ++r)
                    #pragma unroll
                    for (int j = 0; j < 4; ++j)
                        acc[r][k4*4+j] = fmaf(wv[r], av[j], acc[r][k4*4+j]);
            }
        }
    }
    const int gg = blockIdx.x*8 + g;
    #pragma unroll
    for (int r = 0; r < 4; ++r){
        float mx = acc[r][0], mn = acc[r][0], sm = acc[r][0];
        float sq = acc[r][0]*acc[r][0];
        #pragma unroll
        for (int k = 1; k < 32; ++k){
            float v = acc[r][k];
            mx = fmaxf(mx, v); mn = fminf(mn, v);
            sm += v; sq = fmaf(v, v, sq);
        }
        gmax[(size_t)(o0+r)*BM + gg] = mx;
        gmin[(size_t)(o0+r)*BM + gg] = mn;
        atomicAdd(&sSum[o0+r], sm);
        atomicAdd(&sSq[o0+r], sq);
    }
    __syncthreads();
    if (t < 128){
        atomicAdd(&gsum[t], sSum[t]);
        atomicAdd(&gsq[t],  sSq[t]);
    }
}

// ---------------------------------------------------------------------------
// per-channel sum/sumsq over stored y (bf16 channel-major), vectorized
// ---------------------------------------------------------------------------
__global__ __launch_bounds__(256) void k_stats(const u16* __restrict__ y,
                                               float* __restrict__ sum,
                                               float* __restrict__ sumsq){
    int c = blockIdx.x, chunk = blockIdx.y;
    size_t base = (size_t)c*NT + (size_t)chunk*16384;
    const uint2* p = (const uint2*)(y + base);
    float s = 0.0f, qq = 0.0f;
    for (int i = threadIdx.x; i < 4096; i += 256){
        uint2 v = p[i];
        float v0 = bf2f((u16)(v.x & 0xFFFF)), v1 = bf2f((u16)(v.x >> 16));
        float v2 = bf2f((u16)(v.y & 0xFFFF)), v3 = bf2f((u16)(v.y >> 16));
        s += v0 + v1 + v2 + v3;
        qq = fmaf(v0, v0, qq); qq = fmaf(v1, v1, qq);
        qq = fmaf(v2, v2, qq); qq = fmaf(v3, v3, qq);
    }
    #pragma unroll
    for (int off = 32; off > 0; off >>= 1){
        s  += __shfl_down(s,  off, 64);
        qq += __shfl_down(qq, off, 64);
    }
    __shared__ float aS[4], aQ[4];
    int wave = threadIdx.x >> 6, lane = threadIdx.x & 63;
    if (lane == 0){ aS[wave] = s; aQ[wave] = qq; }
    __syncthreads();
    if (threadIdx.x == 0){
        atomicAdd(&sum[c],   aS[0] + aS[1] + aS[2] + aS[3]);
        atomicAdd(&sumsq[c], aQ[0] + aQ[1] + aQ[2] + aQ[3]);
    }
}

// fold BN into affine: s = g*rsqrt(var+eps), t = b - mu*s
__global__ void k_fold(const float* __restrict__ sum, const float* __restrict__ sumsq,
                       const float* __restrict__ gW, const float* __restrict__ bW,
                       float* __restrict__ prm, int C){
    int c = threadIdx.x;
    if (c < C){
        const float inv = 1.0f / (float)NT;
        float mu  = sum[c] * inv;
        float var = sumsq[c] * inv - mu*mu;
        float sc  = gW[c] / sqrtf(var + 1e-5f);
        prm[c]     = sc;
        prm[C + c] = bW[c] - mu*sc;
    }
}

// out[b][o][m] = ReLU(s * (s>=0 ? gmax : gmin) + t)   -- f32 output
__global__ __launch_bounds__(256) void k_final(const float* __restrict__ gmax,
                                               const float* __restrict__ gmin,
                                               const float* __restrict__ prm,
                                               float* __restrict__ out){
    int bo = blockIdx.y;
    int b = bo >> 7, o = bo & 127;
    int m = blockIdx.x*256 + threadIdx.x;
    float sc = prm[o], tt = prm[128 + o];
    size_t i = (size_t)o*BM + b*M_ + m;
    float v = (sc >= 0.0f) ? gmax[i] : gmin[i];
    out[((size_t)(b*128 + o))*M_ + m] = fmaxf(fmaf(v, sc, tt), 0.0f);
}

// ---------------------------------------------------------------------------
extern "C" void kernel_launch(void* const* d_in, const int* in_sizes, int n_in,
                              void* d_out, int out_size, void* d_ws, size_t ws_size,
                              hipStream_t stream){
    const float* loc  = (const float*)d_in[0];
    const float* nloc = (const float*)d_in[1];
    const float* feat = (const float*)d_in[2];
    const float* W1   = (const float*)d_in[3];
    const float* g1   = (const float*)d_in[4];
    const float* b1   = (const float*)d_in[5];
    const float* W2   = (const float*)d_in[6];
    const float* g2   = (const float*)d_in[7];
    const float* b2   = (const float*)d_in[8];
    const float* W3   = (const float*)d_in[9];
    const float* g3   = (const float*)d_in[10];
    const float* b3   = (const float*)d_in[11];
    float* out = (float*)d_out;

    char* ws = (char*)d_ws;
    float* stats = (float*)ws;                       // 512 f @ 0
    float* prm1  = (float*)(ws + 2048);              // 128 f
    float* prm2  = (float*)(ws + 2048 + 512);        // 128 f
    float* prm3  = (float*)(ws + 2048 + 1024);       // 256 f -> ends 4096
    int*   idx   = (int*)(ws + 4096);                // 2 MB
    float* gmax  = (float*)(ws + 2101248);           // 8 MB [128][BM]
    float* gmin  = (float*)(ws + 10489856);          // 8 MB
    float* featT = (float*)(ws + 18878464);          // 16 MB [B][N][64]
    u16*   y1    = (u16*)(ws + 35655680);            // 64 MB [64][NT]
    u16*   y2    = (u16*)(ws + 102764544);           // 64 MB  (ws >= 170 MB proven)

    hipMemsetAsync(stats, 0, 2048, stream);

    k_feat<<<dim3(N_/64, B_), 256, 0, stream>>>(feat, featT);
    k_knn<<<B_*M_, 256, 0, stream>>>(loc, nloc, idx);

    k_conv1t<<<NT/256, 256, 0, stream>>>(idx, loc, nloc, featT, W1, y1);
    k_stats<<<dim3(64, 32), 256, 0, stream>>>(y1, stats + 0, stats + 64);
    k_fold<<<1, 128, 0, stream>>>(stats + 0, stats + 64, g1, b1, prm1, 64);

    k_conv2t<<<NT/256, 256, 0, stream>>>(y1, W2, prm1, y2);
    k_stats<<<dim3(64, 32), 256, 0, stream>>>(y2, stats + 128, stats + 192);
    k_fold<<<1, 128, 0, stream>>>(stats + 128, stats + 192, g2, b2, prm2, 64);

    k_conv3t<<<NT/256, 256, 0, stream>>>(y2, W3, prm2, stats + 256, stats + 384, gmax, gmin);
    k_fold<<<1, 128, 0, stream>>>(stats + 256, stats + 384, g3, b3, prm3, 128);

    k_final<<<dim3(M_/256, B_*128), 256, 0, stream>>>(gmax, gmin, prm3, out);
}

// Round 9
// 617.746 us; speedup vs baseline: 1.7430x; 1.1018x over previous
//
#include <hip/hip_runtime.h>
#include <stdint.h>

// Problem constants
#define B_   16
#define N_   4096
#define M_   1024
#define NT   (B_*M_*32)      // 524288 samples
#define BM   (B_*M_)         // 16384 (b,m) groups

typedef unsigned short u16;
typedef unsigned long long u64;

__device__ __forceinline__ float bf2f(u16 u){
    return __uint_as_float(((unsigned int)u) << 16);
}
__device__ __forceinline__ u16 f2bf(float f){
    unsigned int u = __float_as_uint(f);
    return (u16)((u + 0x7FFFu + ((u >> 16) & 1u)) >> 16);
}

// ---------------------------------------------------------------------------
// features [B][64][N] f32 -> featT [B][N][64] f32
// ---------------------------------------------------------------------------
__global__ __launch_bounds__(256) void k_feat(const float* __restrict__ feat,
                                              float* __restrict__ featT){
    __shared__ float tile[64][65];
    int b  = blockIdx.y;
    int n0 = blockIdx.x * 64;
    for (int t = threadIdx.x; t < 4096; t += 256){
        int c = t >> 6, n = t & 63;
        tile[c][n] = feat[((size_t)(b*64 + c))*N_ + n0 + n];
    }
    __syncthreads();
    for (int t = threadIdx.x; t < 4096; t += 256){
        int n = t >> 6, c = t & 63;
        featT[((size_t)(b*N_) + n0 + n)*64 + c] = tile[c][n];
    }
}

// ---------------------------------------------------------------------------
// exact KNN (32 smallest of 4096): 8-bit LDS-atomic radix histogram passes,
// break to candidate phase when rank-bucket count <= 128; exact finish by
// (key,index) lexicographic rank among candidates (== lax.top_k order; the
// downstream BN/max consumer is order-invariant, so set equality suffices).
// ---------------------------------------------------------------------------
__global__ __launch_bounds__(256) void k_knn(const float* __restrict__ locF,
                                             const float* __restrict__ nlocF,
                                             int* __restrict__ idxOut){
    const int tid  = threadIdx.x;
    const int lane = tid & 63;
    const int q    = blockIdx.x;
    const int b    = q >> 10, m = q & 1023;

    float qx = nlocF[(size_t)(b*M_ + m)*3 + 0];
    float qy = nlocF[(size_t)(b*M_ + m)*3 + 1];
    float qz = nlocF[(size_t)(b*M_ + m)*3 + 2];
    float y2 = __fadd_rn(__fadd_rn(__fmul_rn(qx,qx), __fmul_rn(qy,qy)), __fmul_rn(qz,qz));

    unsigned int key[16];
    const float* lb = locF + (size_t)b*N_*3;
    #pragma unroll
    for (int i = 0; i < 16; ++i){
        int n = i*256 + tid;
        float lx = lb[n*3+0], ly = lb[n*3+1], lz = lb[n*3+2];
        float x2 = __fadd_rn(__fadd_rn(__fmul_rn(lx,lx), __fmul_rn(ly,ly)), __fmul_rn(lz,lz));
        float dt = __fadd_rn(__fadd_rn(__fmul_rn(qx,lx), __fmul_rn(qy,ly)), __fmul_rn(qz,lz));
        float d2 = __fsub_rn(__fadd_rn(y2, x2), __fmul_rn(2.0f, dt));
        d2 = fmaxf(d2, 0.0f);                  // uint order == float order
        key[i] = __float_as_uint(d2);
    }

    __shared__ unsigned int hist[256];
    __shared__ u64 cand[128];
    __shared__ int sOut[32];
    __shared__ int outCnt, candCnt;

    unsigned int prefix = 0;
    int R = 32;
    int fshift = 24;

    for (int p = 0; p < 4; ++p){
        const int sh = 24 - 8*p;
        hist[tid] = 0;
        if (p == 0 && tid == 0){ outCnt = 0; candCnt = 0; }
        __syncthreads();
        if (p == 0){
            #pragma unroll
            for (int i = 0; i < 16; ++i)
                atomicAdd(&hist[key[i] >> 24], 1u);
        } else {
            #pragma unroll
            for (int i = 0; i < 16; ++i){
                unsigned int k = key[i];
                if ((k >> (sh+8)) == (prefix >> (sh+8)))
                    atomicAdd(&hist[(k >> sh) & 255u], 1u);
            }
        }
        __syncthreads();
        // redundant per-wave scan of the 256 buckets
        uint4 h = *(const uint4*)&hist[lane << 2];
        int tot = (int)(h.x + h.y + h.z + h.w);
        int v = tot;
        #pragma unroll
        for (int st = 1; st < 64; st <<= 1){
            int u = __shfl_up(v, st, 64);
            if (lane >= st) v += u;
        }
        u64 bal = __ballot(v >= R);
        int Ls = __ffsll((unsigned long long)bal) - 1;
        int exclS = __shfl(v - tot, Ls, 64);
        int hx = __shfl((int)h.x, Ls, 64), hy = __shfl((int)h.y, Ls, 64);
        int hz = __shfl((int)h.z, Ls, 64), hw = __shfl((int)h.w, Ls, 64);
        int c0 = exclS + hx, c1 = c0 + hy, c2 = c1 + hz;
        int jj    = (c0 >= R) ? 0 : (c1 >= R) ? 1 : (c2 >= R) ? 2 : 3;
        int below = (jj == 0) ? exclS : (jj == 1) ? c0 : (jj == 2) ? c1 : c2;
        int cnt   = (jj == 0) ? hx : (jj == 1) ? hy : (jj == 2) ? hz : hw;
        prefix |= ((unsigned int)(Ls*4 + jj)) << sh;
        R -= below;
        fshift = sh;
        __syncthreads();                      // hist reusable / done reading
        if (cnt <= 128) break;                // uniform decision
    }

    // emission: keys below prefix (exactly 32-R of them) + candidates (== prefix)
    const unsigned int pp = prefix >> fshift;
    #pragma unroll
    for (int i = 0; i < 16; ++i){
        unsigned int kp = key[i] >> fshift;
        int n = i*256 + tid;
        if (kp < pp){
            int pos = atomicAdd(&outCnt, 1);
            if (pos < 32) sOut[pos] = n;
        } else if (kp == pp){
            int pos = atomicAdd(&candCnt, 1);
            if (pos < 128) cand[pos] = (((u64)key[i]) << 32) | (unsigned int)n;
        }
    }
    __syncthreads();
    int c = candCnt < 128 ? candCnt : 128;
    int base = outCnt;                        // == 32 - R
    if (tid < c){
        u64 me = cand[tid];
        int rank = 0;
        for (int j = 0; j < c; ++j) rank += (cand[j] < me) ? 1 : 0;
        if (rank < R) sOut[base + rank] = (int)(me & 0xFFFFFFFFull);
    }
    __syncthreads();
    if (tid < 32) idxOut[(size_t)q*32 + tid] = sOut[tid];
}

// ---------------------------------------------------------------------------
// conv1 tiled: thread = (o-block 16, s-block 4); gather staged via LDS.
// ---------------------------------------------------------------------------
__global__ __launch_bounds__(256) void k_conv1t(const int* __restrict__ idx,
                                                const float* __restrict__ locF,
                                                const float* __restrict__ nlocF,
                                                const float* __restrict__ featT,
                                                const float* __restrict__ W1,
                                                u16* __restrict__ y1){
    __shared__ float Wl[67*64];     // [c][o]
    __shared__ float At[16*256];    // [c_local][s_local]
    const int t  = threadIdx.x;
    const int s0 = blockIdx.x * 256;
    for (int i = t; i < 67*64; i += 256){
        int c = i >> 6, o = i & 63;
        Wl[i] = W1[o*67 + c];
    }
    __syncthreads();

    const int ob = t >> 6;          // 0..3
    const int sb = t & 63;          // 0..63
    const int o0 = ob*16;
    const int b  = s0 >> 15;
    float acc[16][4];

    {
        int4 nn = *(const int4*)&idx[s0 + sb*4];
        int ns[4] = {nn.x, nn.y, nn.z, nn.w};
        int m = ((s0 + sb*4) >> 5) & 1023;
        float qx = nlocF[(size_t)(b*M_ + m)*3 + 0];
        float qy = nlocF[(size_t)(b*M_ + m)*3 + 1];
        float qz = nlocF[(size_t)(b*M_ + m)*3 + 2];
        float r0[4], r1[4], r2[4];
        #pragma unroll
        for (int j = 0; j < 4; ++j){
            int n = ns[j]; if ((unsigned)n >= N_) n = 0;
            const float* lp = &locF[(size_t)(b*N_ + n)*3];
            r0[j] = lp[0] - qx; r1[j] = lp[1] - qy; r2[j] = lp[2] - qz;
        }
        #pragma unroll
        for (int i = 0; i < 16; ++i){
            float w0 = Wl[o0 + i], w1 = Wl[64 + o0 + i], w2 = Wl[128 + o0 + i];
            #pragma unroll
            for (int j = 0; j < 4; ++j)
                acc[i][j] = fmaf(w2, r2[j], fmaf(w1, r1[j], w0*r0[j]));
        }
    }

    for (int pass = 0; pass < 4; ++pass){
        __syncthreads();
        {
            int n = idx[s0 + t]; if ((unsigned)n >= N_) n = 0;
            const float4* fr = (const float4*)&featT[((size_t)(b*N_) + n)*64 + pass*16];
            #pragma unroll
            for (int q = 0; q < 4; ++q){
                float4 f = fr[q];
                At[(q*4+0)*256 + t] = f.x;
                At[(q*4+1)*256 + t] = f.y;
                At[(q*4+2)*256 + t] = f.z;
                At[(q*4+3)*256 + t] = f.w;
            }
        }
        __syncthreads();
        const float4* Wrow = (const float4*)&Wl[(3 + pass*16)*64];
        #pragma unroll
        for (int c = 0; c < 16; ++c){
            float4 a = *(const float4*)&At[c*256 + sb*4];
            float av[4] = {a.x, a.y, a.z, a.w};
            #pragma unroll
            for (int q = 0; q < 4; ++q){
                float4 w = Wrow[c*16 + ob*4 + q];
                float wv[4] = {w.x, w.y, w.z, w.w};
                #pragma unroll
                for (int r = 0; r < 4; ++r)
                    #pragma unroll
                    for (int j = 0; j < 4; ++j)
                        acc[q*4+r][j] = fmaf(wv[r], av[j], acc[q*4+r][j]);
            }
        }
    }
    #pragma unroll
    for (int i = 0; i < 16; ++i){
        ushort4 pk;
        pk.x = f2bf(acc[i][0]); pk.y = f2bf(acc[i][1]);
        pk.z = f2bf(acc[i][2]); pk.w = f2bf(acc[i][3]);
        *(ushort4*)&y1[(size_t)(o0+i)*NT + s0 + sb*4] = pk;
    }
}

// ---------------------------------------------------------------------------
// conv2 tiled
// ---------------------------------------------------------------------------
__global__ __launch_bounds__(256) void k_conv2t(const u16* __restrict__ yin,
                                                const float* __restrict__ W2,
                                                const float* __restrict__ prm,
                                                u16* __restrict__ yout){
    __shared__ float Wl[64*64];     // [c][o]
    __shared__ float At[16*256];
    __shared__ float sS[64], sT[64];
    const int t  = threadIdx.x;
    const int s0 = blockIdx.x * 256;
    for (int i = t; i < 64*64; i += 256){
        int c = i >> 6, o = i & 63;
        Wl[i] = W2[o*64 + c];
    }
    if (t < 64){ sS[t] = prm[t]; sT[t] = prm[64 + t]; }

    const int ob = t >> 6, sb = t & 63, o0 = ob*16;
    float acc[16][4];
    #pragma unroll
    for (int i = 0; i < 16; ++i)
        #pragma unroll
        for (int j = 0; j < 4; ++j) acc[i][j] = 0.0f;

    for (int pass = 0; pass < 4; ++pass){
        __syncthreads();
        #pragma unroll
        for (int rep = 0; rep < 2; ++rep){
            int v = rep*256 + t;
            int row = v >> 5, ch = v & 31;
            int c = pass*16 + row;
            uint4 pk = *(const uint4*)&yin[(size_t)c*NT + s0 + ch*8];
            float sc = sS[c], tt = sT[c];
            unsigned int w4[4] = {pk.x, pk.y, pk.z, pk.w};
            float f[8];
            #pragma unroll
            for (int q = 0; q < 4; ++q){
                f[2*q]   = fmaxf(fmaf(bf2f((u16)(w4[q] & 0xFFFF)), sc, tt), 0.0f);
                f[2*q+1] = fmaxf(fmaf(bf2f((u16)(w4[q] >> 16)),   sc, tt), 0.0f);
            }
            float4 f1 = {f[0], f[1], f[2], f[3]};
            float4 f2 = {f[4], f[5], f[6], f[7]};
            *(float4*)&At[row*256 + ch*8]     = f1;
            *(float4*)&At[row*256 + ch*8 + 4] = f2;
        }
        __syncthreads();
        const float4* Wrow = (const float4*)&Wl[(pass*16)*64];
        #pragma unroll
        for (int c = 0; c < 16; ++c){
            float4 a = *(const float4*)&At[c*256 + sb*4];
            float av[4] = {a.x, a.y, a.z, a.w};
            #pragma unroll
            for (int q = 0; q < 4; ++q){
                float4 w = Wrow[c*16 + ob*4 + q];
                float wv[4] = {w.x, w.y, w.z, w.w};
                #pragma unroll
                for (int r = 0; r < 4; ++r)
                    #pragma unroll
                    for (int j = 0; j < 4; ++j)
                        acc[q*4+r][j] = fmaf(wv[r], av[j], acc[q*4+r][j]);
            }
        }
    }
    #pragma unroll
    for (int i = 0; i < 16; ++i){
        ushort4 pk;
        pk.x = f2bf(acc[i][0]); pk.y = f2bf(acc[i][1]);
        pk.z = f2bf(acc[i][2]); pk.w = f2bf(acc[i][3]);
        *(ushort4*)&yout[(size_t)(o0+i)*NT + s0 + sb*4] = pk;
    }
}

// ---------------------------------------------------------------------------
// conv3 tiled + fused stats/minmax (in-register k reductions)
// ---------------------------------------------------------------------------
__global__ __launch_bounds__(256) void k_conv3t(const u16* __restrict__ yin,
                                                const float* __restrict__ W3,
                                                const float* __restrict__ prm,
                                                float* __restrict__ gsum, float* __restrict__ gsq,
                                                float* __restrict__ gmax, float* __restrict__ gmin){
    __shared__ float Wl[64*128];    // [c][o]
    __shared__ float At[16*256];
    __shared__ float sS[64], sT[64];
    __shared__ float sSum[128], sSq[128];
    const int t  = threadIdx.x;
    const int s0 = blockIdx.x * 256;
    for (int i = t; i < 64*128; i += 256){
        int c = i >> 7, o = i & 127;
        Wl[i] = W3[o*64 + c];
    }
    if (t < 64){ sS[t] = prm[t]; sT[t] = prm[64 + t]; }
    if (t < 128){ sSum[t] = 0.0f; sSq[t] = 0.0f; }

    const int g  = t >> 5;
    const int oq = t & 31;
    const int o0 = oq*4;
    float acc[4][32];
    #pragma unroll
    for (int r = 0; r < 4; ++r)
        #pragma unroll
        for (int k = 0; k < 32; ++k) acc[r][k] = 0.0f;

    for (int pass = 0; pass < 4; ++pass){
        __syncthreads();
        #pragma unroll
        for (int rep = 0; rep < 2; ++rep){
            int v = rep*256 + t;
            int row = v >> 5, ch = v & 31;
            int c = pass*16 + row;
            uint4 pk = *(const uint4*)&yin[(size_t)c*NT + s0 + ch*8];
            float sc = sS[c], tt = sT[c];
            unsigned int w4[4] = {pk.x, pk.y, pk.z, pk.w};
            float f[8];
            #pragma unroll
            for (int q = 0; q < 4; ++q){
                f[2*q]   = fmaxf(fmaf(bf2f((u16)(w4[q] & 0xFFFF)), sc, tt), 0.0f);
                f[2*q+1] = fmaxf(fmaf(bf2f((u16)(w4[q] >> 16)),   sc, tt), 0.0f);
            }
            float4 f1 = {f[0], f[1], f[2], f[3]};
            float4 f2 = {f[4], f[5], f[6], f[7]};
            *(float4*)&At[row*256 + ch*8]     = f1;
            *(float4*)&At[row*256 + ch*8 + 4] = f2;
        }
        __syncthreads();
        #pragma unroll
        for (int c = 0; c < 16; ++c){
            float4 w = *(const float4*)&Wl[(pass*16 + c)*128 + o0];
            float wv[4] = {w.x, w.y, w.z, w.w};
            const float* ap = &At[c*256 + g*32];
            #pragma unroll
            for (int k4 = 0; k4 < 8; ++k4){
                float4 a = *(const float4*)&ap[k4*4];
                float av[4] = {a.x, a.y, a.z, a.w};
                #pragma unroll
                for (int r = 0; r < 4; ++r)
                    #pragma unroll
                    for (int j = 0; j < 4; ++j)
                        acc[r][k4*4+j] = fmaf(wv[r], av[j], acc[r][k4*4+j]);
            }
        }
    }
    const int gg = blockIdx.x*8 + g;
    #pragma unroll
    for (int r = 0; r < 4; ++r){
        float mx = acc[r][0], mn = acc[r][0], sm = acc[r][0];
        float sq = acc[r][0]*acc[r][0];
        #pragma unroll
        for (int k = 1; k < 32; ++k){
            float v = acc[r][k];
            mx = fmaxf(mx, v); mn = fminf(mn, v);
            sm += v; sq = fmaf(v, v, sq);
        }
        gmax[(size_t)(o0+r)*BM + gg] = mx;
        gmin[(size_t)(o0+r)*BM + gg] = mn;
        atomicAdd(&sSum[o0+r], sm);
        atomicAdd(&sSq[o0+r], sq);
    }
    __syncthreads();
    if (t < 128){
        atomicAdd(&gsum[t], sSum[t]);
        atomicAdd(&gsq[t],  sSq[t]);
    }
}

// ---------------------------------------------------------------------------
// per-channel sum/sumsq over stored y (bf16 channel-major), vectorized
// ---------------------------------------------------------------------------
__global__ __launch_bounds__(256) void k_stats(const u16* __restrict__ y,
                                               float* __restrict__ sum,
                                               float* __restrict__ sumsq){
    int c = blockIdx.x, chunk = blockIdx.y;
    size_t base = (size_t)c*NT + (size_t)chunk*16384;
    const uint2* p = (const uint2*)(y + base);
    float s = 0.0f, qq = 0.0f;
    for (int i = threadIdx.x; i < 4096; i += 256){
        uint2 v = p[i];
        float v0 = bf2f((u16)(v.x & 0xFFFF)), v1 = bf2f((u16)(v.x >> 16));
        float v2 = bf2f((u16)(v.y & 0xFFFF)), v3 = bf2f((u16)(v.y >> 16));
        s += v0 + v1 + v2 + v3;
        qq = fmaf(v0, v0, qq); qq = fmaf(v1, v1, qq);
        qq = fmaf(v2, v2, qq); qq = fmaf(v3, v3, qq);
    }
    #pragma unroll
    for (int off = 32; off > 0; off >>= 1){
        s  += __shfl_down(s,  off, 64);
        qq += __shfl_down(qq, off, 64);
    }
    __shared__ float aS[4], aQ[4];
    int wave = threadIdx.x >> 6, lane = threadIdx.x & 63;
    if (lane == 0){ aS[wave] = s; aQ[wave] = qq; }
    __syncthreads();
    if (threadIdx.x == 0){
        atomicAdd(&sum[c],   aS[0] + aS[1] + aS[2] + aS[3]);
        atomicAdd(&sumsq[c], aQ[0] + aQ[1] + aQ[2] + aQ[3]);
    }
}

// fold BN into affine: s = g*rsqrt(var+eps), t = b - mu*s
__global__ void k_fold(const float* __restrict__ sum, const float* __restrict__ sumsq,
                       const float* __restrict__ gW, const float* __restrict__ bW,
                       float* __restrict__ prm, int C){
    int c = threadIdx.x;
    if (c < C){
        const float inv = 1.0f / (float)NT;
        float mu  = sum[c] * inv;
        float var = sumsq[c] * inv - mu*mu;
        float sc  = gW[c] / sqrtf(var + 1e-5f);
        prm[c]     = sc;
        prm[C + c] = bW[c] - mu*sc;
    }
}

// out[b][o][m] = ReLU(s * (s>=0 ? gmax : gmin) + t)   -- f32 output
__global__ __launch_bounds__(256) void k_final(const float* __restrict__ gmax,
                                               const float* __restrict__ gmin,
                                               const float* __restrict__ prm,
                                               float* __restrict__ out){
    int bo = blockIdx.y;
    int b = bo >> 7, o = bo & 127;
    int m = blockIdx.x*256 + threadIdx.x;
    float sc = prm[o], tt = prm[128 + o];
    size_t i = (size_t)o*BM + b*M_ + m;
    float v = (sc >= 0.0f) ? gmax[i] : gmin[i];
    out[((size_t)(b*128 + o))*M_ + m] = fmaxf(fmaf(v, sc, tt), 0.0f);
}

// ---------------------------------------------------------------------------
extern "C" void kernel_launch(void* const* d_in, const int* in_sizes, int n_in,
                              void* d_out, int out_size, void* d_ws, size_t ws_size,
                              hipStream_t stream){
    const float* loc  = (const float*)d_in[0];
    const float* nloc = (const float*)d_in[1];
    const float* feat = (const float*)d_in[2];
    const float* W1   = (const float*)d_in[3];
    const float* g1   = (const float*)d_in[4];
    const float* b1   = (const float*)d_in[5];
    const float* W2   = (const float*)d_in[6];
    const float* g2   = (const float*)d_in[7];
    const float* b2   = (const float*)d_in[8];
    const float* W3   = (const float*)d_in[9];
    const float* g3   = (const float*)d_in[10];
    const float* b3   = (const float*)d_in[11];
    float* out = (float*)d_out;

    char* ws = (char*)d_ws;
    float* stats = (float*)ws;                       // 512 f @ 0
    float* prm1  = (float*)(ws + 2048);              // 128 f
    float* prm2  = (float*)(ws + 2048 + 512);        // 128 f
    float* prm3  = (float*)(ws + 2048 + 1024);       // 256 f -> ends 4096
    int*   idx   = (int*)(ws + 4096);                // 2 MB
    float* gmax  = (float*)(ws + 2101248);           // 8 MB [128][BM]
    float* gmin  = (float*)(ws + 10489856);          // 8 MB
    float* featT = (float*)(ws + 18878464);          // 16 MB [B][N][64]
    u16*   y1    = (u16*)(ws + 35655680);            // 64 MB [64][NT]
    u16*   y2    = (u16*)(ws + 102764544);           // 64 MB  (ws >= 170 MB proven)

    hipMemsetAsync(stats, 0, 2048, stream);

    k_feat<<<dim3(N_/64, B_), 256, 0, stream>>>(feat, featT);
    k_knn<<<B_*M_, 256, 0, stream>>>(loc, nloc, idx);

    k_conv1t<<<NT/256, 256, 0, stream>>>(idx, loc, nloc, featT, W1, y1);
    k_stats<<<dim3(64, 32), 256, 0, stream>>>(y1, stats + 0, stats + 64);
    k_fold<<<1, 128, 0, stream>>>(stats + 0, stats + 64, g1, b1, prm1, 64);

    k_conv2t<<<NT/256, 256, 0, stream>>>(y1, W2, prm1, y2);
    k_stats<<<dim3(64, 32), 256, 0, stream>>>(y2, stats + 128, stats + 192);
    k_fold<<<1, 128, 0, stream>>>(stats + 128, stats + 192, g2, b2, prm2, 64);

    k_conv3t<<<NT/256, 256, 0, stream>>>(y2, W3, prm2, stats + 256, stats + 384, gmax, gmin);
    k_fold<<<1, 128, 0, stream>>>(stats + 256, stats + 384, g3, b3, prm3, 128);

    k_final<<<dim3(M_/256, B_*128), 256, 0, stream>>>(gmax, gmin, prm3, out);
}

// Round 10
// 598.941 us; speedup vs baseline: 1.7977x; 1.0314x over previous
//
#include <hip/hip_runtime.h>
#include <stdint.h>

// Problem constants
#define B_   16
#define N_   4096
#define M_   1024
#define NT   (B_*M_*32)      // 524288 samples
#define BM   (B_*M_)         // 16384 (b,m) groups

typedef unsigned short u16;
typedef unsigned long long u64;
typedef __attribute__((ext_vector_type(8))) short short8;   // 8 bf16 (4 VGPRs)
typedef __attribute__((ext_vector_type(4))) float f32x4;    // MFMA C/D

__device__ __forceinline__ float bf2f(u16 u){
    return __uint_as_float(((unsigned int)u) << 16);
}
__device__ __forceinline__ u16 f2bf(float f){
    unsigned int u = __float_as_uint(f);
    return (u16)((u + 0x7FFFu + ((u >> 16) & 1u)) >> 16);
}

// ---------------------------------------------------------------------------
// features [B][64][N] f32 -> featT [B][N][64] f32
// ---------------------------------------------------------------------------
__global__ __launch_bounds__(256) void k_feat(const float* __restrict__ feat,
                                              float* __restrict__ featT){
    __shared__ float tile[64][65];
    int b  = blockIdx.y;
    int n0 = blockIdx.x * 64;
    for (int t = threadIdx.x; t < 4096; t += 256){
        int c = t >> 6, n = t & 63;
        tile[c][n] = feat[((size_t)(b*64 + c))*N_ + n0 + n];
    }
    __syncthreads();
    for (int t = threadIdx.x; t < 4096; t += 256){
        int n = t >> 6, c = t & 63;
        featT[((size_t)(b*N_) + n0 + n)*64 + c] = tile[c][n];
    }
}

// ---------------------------------------------------------------------------
// exact KNN (32 smallest of 4096): 8-bit LDS-atomic radix histogram passes,
// break when rank-bucket <= 128 candidates; exact (key,index) finish.
// ---------------------------------------------------------------------------
__global__ __launch_bounds__(256) void k_knn(const float* __restrict__ locF,
                                             const float* __restrict__ nlocF,
                                             int* __restrict__ idxOut){
    const int tid  = threadIdx.x;
    const int lane = tid & 63;
    const int q    = blockIdx.x;
    const int b    = q >> 10, m = q & 1023;

    float qx = nlocF[(size_t)(b*M_ + m)*3 + 0];
    float qy = nlocF[(size_t)(b*M_ + m)*3 + 1];
    float qz = nlocF[(size_t)(b*M_ + m)*3 + 2];
    float y2 = __fadd_rn(__fadd_rn(__fmul_rn(qx,qx), __fmul_rn(qy,qy)), __fmul_rn(qz,qz));

    unsigned int key[16];
    const float* lb = locF + (size_t)b*N_*3;
    #pragma unroll
    for (int i = 0; i < 16; ++i){
        int n = i*256 + tid;
        float lx = lb[n*3+0], ly = lb[n*3+1], lz = lb[n*3+2];
        float x2 = __fadd_rn(__fadd_rn(__fmul_rn(lx,lx), __fmul_rn(ly,ly)), __fmul_rn(lz,lz));
        float dt = __fadd_rn(__fadd_rn(__fmul_rn(qx,lx), __fmul_rn(qy,ly)), __fmul_rn(qz,lz));
        float d2 = __fsub_rn(__fadd_rn(y2, x2), __fmul_rn(2.0f, dt));
        d2 = fmaxf(d2, 0.0f);
        key[i] = __float_as_uint(d2);
    }

    __shared__ unsigned int hist[256];
    __shared__ u64 cand[128];
    __shared__ int sOut[32];
    __shared__ int outCnt, candCnt;

    unsigned int prefix = 0;
    int R = 32;
    int fshift = 24;

    for (int p = 0; p < 4; ++p){
        const int sh = 24 - 8*p;
        hist[tid] = 0;
        if (p == 0 && tid == 0){ outCnt = 0; candCnt = 0; }
        __syncthreads();
        if (p == 0){
            #pragma unroll
            for (int i = 0; i < 16; ++i)
                atomicAdd(&hist[key[i] >> 24], 1u);
        } else {
            #pragma unroll
            for (int i = 0; i < 16; ++i){
                unsigned int k = key[i];
                if ((k >> (sh+8)) == (prefix >> (sh+8)))
                    atomicAdd(&hist[(k >> sh) & 255u], 1u);
            }
        }
        __syncthreads();
        uint4 h = *(const uint4*)&hist[lane << 2];
        int tot = (int)(h.x + h.y + h.z + h.w);
        int v = tot;
        #pragma unroll
        for (int st = 1; st < 64; st <<= 1){
            int u = __shfl_up(v, st, 64);
            if (lane >= st) v += u;
        }
        u64 bal = __ballot(v >= R);
        int Ls = __ffsll((unsigned long long)bal) - 1;
        int exclS = __shfl(v - tot, Ls, 64);
        int hx = __shfl((int)h.x, Ls, 64), hy = __shfl((int)h.y, Ls, 64);
        int hz = __shfl((int)h.z, Ls, 64), hw = __shfl((int)h.w, Ls, 64);
        int c0 = exclS + hx, c1 = c0 + hy, c2 = c1 + hz;
        int jj    = (c0 >= R) ? 0 : (c1 >= R) ? 1 : (c2 >= R) ? 2 : 3;
        int below = (jj == 0) ? exclS : (jj == 1) ? c0 : (jj == 2) ? c1 : c2;
        int cnt   = (jj == 0) ? hx : (jj == 1) ? hy : (jj == 2) ? hz : hw;
        prefix |= ((unsigned int)(Ls*4 + jj)) << sh;
        R -= below;
        fshift = sh;
        __syncthreads();
        if (cnt <= 128) break;
    }

    const unsigned int pp = prefix >> fshift;
    #pragma unroll
    for (int i = 0; i < 16; ++i){
        unsigned int kp = key[i] >> fshift;
        int n = i*256 + tid;
        if (kp < pp){
            int pos = atomicAdd(&outCnt, 1);
            if (pos < 32) sOut[pos] = n;
        } else if (kp == pp){
            int pos = atomicAdd(&candCnt, 1);
            if (pos < 128) cand[pos] = (((u64)key[i]) << 32) | (unsigned int)n;
        }
    }
    __syncthreads();
    int c = candCnt < 128 ? candCnt : 128;
    int base = outCnt;
    if (tid < c){
        u64 me = cand[tid];
        int rank = 0;
        for (int j = 0; j < c; ++j) rank += (cand[j] < me) ? 1 : 0;
        if (rank < R) sOut[base + rank] = (int)(me & 0xFFFFFFFFull);
    }
    __syncthreads();
    if (tid < 32) idxOut[(size_t)q*32 + tid] = sOut[tid];
}

// ---------------------------------------------------------------------------
// conv1 tiled: thread = (o-block 16, s-block 4); gather staged via LDS.
// ---------------------------------------------------------------------------
__global__ __launch_bounds__(256) void k_conv1t(const int* __restrict__ idx,
                                                const float* __restrict__ locF,
                                                const float* __restrict__ nlocF,
                                                const float* __restrict__ featT,
                                                const float* __restrict__ W1,
                                                u16* __restrict__ y1){
    __shared__ float Wl[67*64];     // [c][o]
    __shared__ float At[16*256];    // [c_local][s_local]
    const int t  = threadIdx.x;
    const int s0 = blockIdx.x * 256;
    for (int i = t; i < 67*64; i += 256){
        int c = i >> 6, o = i & 63;
        Wl[i] = W1[o*67 + c];
    }
    __syncthreads();

    const int ob = t >> 6;
    const int sb = t & 63;
    const int o0 = ob*16;
    const int b  = s0 >> 15;
    float acc[16][4];

    {
        int4 nn = *(const int4*)&idx[s0 + sb*4];
        int ns[4] = {nn.x, nn.y, nn.z, nn.w};
        int m = ((s0 + sb*4) >> 5) & 1023;
        float qx = nlocF[(size_t)(b*M_ + m)*3 + 0];
        float qy = nlocF[(size_t)(b*M_ + m)*3 + 1];
        float qz = nlocF[(size_t)(b*M_ + m)*3 + 2];
        float r0[4], r1[4], r2[4];
        #pragma unroll
        for (int j = 0; j < 4; ++j){
            int n = ns[j]; if ((unsigned)n >= N_) n = 0;
            const float* lp = &locF[(size_t)(b*N_ + n)*3];
            r0[j] = lp[0] - qx; r1[j] = lp[1] - qy; r2[j] = lp[2] - qz;
        }
        #pragma unroll
        for (int i = 0; i < 16; ++i){
            float w0 = Wl[o0 + i], w1 = Wl[64 + o0 + i], w2 = Wl[128 + o0 + i];
            #pragma unroll
            for (int j = 0; j < 4; ++j)
                acc[i][j] = fmaf(w2, r2[j], fmaf(w1, r1[j], w0*r0[j]));
        }
    }

    for (int pass = 0; pass < 4; ++pass){
        __syncthreads();
        {
            int n = idx[s0 + t]; if ((unsigned)n >= N_) n = 0;
            const float4* fr = (const float4*)&featT[((size_t)(b*N_) + n)*64 + pass*16];
            #pragma unroll
            for (int q = 0; q < 4; ++q){
                float4 f = fr[q];
                At[(q*4+0)*256 + t] = f.x;
                At[(q*4+1)*256 + t] = f.y;
                At[(q*4+2)*256 + t] = f.z;
                At[(q*4+3)*256 + t] = f.w;
            }
        }
        __syncthreads();
        const float4* Wrow = (const float4*)&Wl[(3 + pass*16)*64];
        #pragma unroll
        for (int c = 0; c < 16; ++c){
            float4 a = *(const float4*)&At[c*256 + sb*4];
            float av[4] = {a.x, a.y, a.z, a.w};
            #pragma unroll
            for (int q = 0; q < 4; ++q){
                float4 w = Wrow[c*16 + ob*4 + q];
                float wv[4] = {w.x, w.y, w.z, w.w};
                #pragma unroll
                for (int r = 0; r < 4; ++r)
                    #pragma unroll
                    for (int j = 0; j < 4; ++j)
                        acc[q*4+r][j] = fmaf(wv[r], av[j], acc[q*4+r][j]);
            }
        }
    }
    #pragma unroll
    for (int i = 0; i < 16; ++i){
        ushort4 pk;
        pk.x = f2bf(acc[i][0]); pk.y = f2bf(acc[i][1]);
        pk.z = f2bf(acc[i][2]); pk.w = f2bf(acc[i][3]);
        *(ushort4*)&y1[(size_t)(o0+i)*NT + s0 + sb*4] = pk;
    }
}

// ---------------------------------------------------------------------------
// conv2 tiled
// ---------------------------------------------------------------------------
__global__ __launch_bounds__(256) void k_conv2t(const u16* __restrict__ yin,
                                                const float* __restrict__ W2,
                                                const float* __restrict__ prm,
                                                u16* __restrict__ yout){
    __shared__ float Wl[64*64];     // [c][o]
    __shared__ float At[16*256];
    __shared__ float sS[64], sT[64];
    const int t  = threadIdx.x;
    const int s0 = blockIdx.x * 256;
    for (int i = t; i < 64*64; i += 256){
        int c = i >> 6, o = i & 63;
        Wl[i] = W2[o*64 + c];
    }
    if (t < 64){ sS[t] = prm[t]; sT[t] = prm[64 + t]; }

    const int ob = t >> 6, sb = t & 63, o0 = ob*16;
    float acc[16][4];
    #pragma unroll
    for (int i = 0; i < 16; ++i)
        #pragma unroll
        for (int j = 0; j < 4; ++j) acc[i][j] = 0.0f;

    for (int pass = 0; pass < 4; ++pass){
        __syncthreads();
        #pragma unroll
        for (int rep = 0; rep < 2; ++rep){
            int v = rep*256 + t;
            int row = v >> 5, ch = v & 31;
            int c = pass*16 + row;
            uint4 pk = *(const uint4*)&yin[(size_t)c*NT + s0 + ch*8];
            float sc = sS[c], tt = sT[c];
            unsigned int w4[4] = {pk.x, pk.y, pk.z, pk.w};
            float f[8];
            #pragma unroll
            for (int q = 0; q < 4; ++q){
                f[2*q]   = fmaxf(fmaf(bf2f((u16)(w4[q] & 0xFFFF)), sc, tt), 0.0f);
                f[2*q+1] = fmaxf(fmaf(bf2f((u16)(w4[q] >> 16)),   sc, tt), 0.0f);
            }
            float4 f1 = {f[0], f[1], f[2], f[3]};
            float4 f2 = {f[4], f[5], f[6], f[7]};
            *(float4*)&At[row*256 + ch*8]     = f1;
            *(float4*)&At[row*256 + ch*8 + 4] = f2;
        }
        __syncthreads();
        const float4* Wrow = (const float4*)&Wl[(pass*16)*64];
        #pragma unroll
        for (int c = 0; c < 16; ++c){
            float4 a = *(const float4*)&At[c*256 + sb*4];
            float av[4] = {a.x, a.y, a.z, a.w};
            #pragma unroll
            for (int q = 0; q < 4; ++q){
                float4 w = Wrow[c*16 + ob*4 + q];
                float wv[4] = {w.x, w.y, w.z, w.w};
                #pragma unroll
                for (int r = 0; r < 4; ++r)
                    #pragma unroll
                    for (int j = 0; j < 4; ++j)
                        acc[q*4+r][j] = fmaf(wv[r], av[j], acc[q*4+r][j]);
            }
        }
    }
    #pragma unroll
    for (int i = 0; i < 16; ++i){
        ushort4 pk;
        pk.x = f2bf(acc[i][0]); pk.y = f2bf(acc[i][1]);
        pk.z = f2bf(acc[i][2]); pk.w = f2bf(acc[i][3]);
        *(ushort4*)&yout[(size_t)(o0+i)*NT + s0 + sb*4] = pk;
    }
}

// ---------------------------------------------------------------------------
// conv3 via MFMA (bf16 in, f32 acc) + fused stats/minmax.
// Block = 256 samples. A = W3 (128x64), B = relu(affine(y2)) (64x256).
// Frags pre-packed in LDS in per-lane order (lane*16B contiguous).
// Layouts (guide §3, m89/m91/m120): A[m=lane&15][k=quad*8+j],
// B[k=quad*8+j][n=lane&15], D row=(quad*4+reg), col=lane&15.
// ---------------------------------------------------------------------------
__global__ __launch_bounds__(256) void k_conv3m(const u16* __restrict__ yin,
                                                const float* __restrict__ W3,
                                                const float* __restrict__ prm,
                                                float* __restrict__ gsum, float* __restrict__ gsq,
                                                float* __restrict__ gmax, float* __restrict__ gmin){
    __shared__ uint4 bfA[1024];     // W3 bf16 frags: (mt*2+kk)*64+lane   (16 KB)
    __shared__ uint4 bfB[2048];     // act bf16 frags: (nt*2+kk)*64+lane  (32 KB)
    __shared__ float sS[64], sT[64];
    __shared__ float sSum[128], sSq[128];
    const int t  = threadIdx.x;
    const int s0 = blockIdx.x * 256;

    if (t < 64){ sS[t] = prm[t]; sT[t] = prm[64 + t]; }
    if (t < 128){ sSum[t] = 0.0f; sSq[t] = 0.0f; }
    __syncthreads();

    // stage A: W3 [128][64] f32 -> bf16 frags
    #pragma unroll
    for (int rep = 0; rep < 4; ++rep){
        int cid = rep*256 + t;
        int ln  = cid & 63;
        int kk  = (cid >> 6) & 1;
        int mt  = cid >> 7;
        int m   = mt*16 + (ln & 15);
        int k0  = kk*32 + (ln >> 4)*8;
        const float* wp = &W3[m*64 + k0];
        unsigned int d[4];
        #pragma unroll
        for (int h = 0; h < 4; ++h)
            d[h] = (unsigned int)f2bf(wp[2*h]) | (((unsigned int)f2bf(wp[2*h+1])) << 16);
        bfA[cid] = make_uint4(d[0], d[1], d[2], d[3]);
    }

    // stage B: y2 channel-major, coalesced load; affine+relu; bf16 frags
    {
        int oct = t >> 5;            // channel octet: c = oct*8 .. +7
        int sg  = t & 31;            // samples sg*8 .. +7 (local)
        int c0  = oct*8;
        int kk  = oct >> 2;
        int qd  = oct & 3;
        int nt  = sg >> 1;
        u16 rb[8][8];                // [j (=c-c0)][i (=sample)]
        #pragma unroll
        for (int j = 0; j < 8; ++j){
            int c = c0 + j;
            uint4 pk = *(const uint4*)&yin[(size_t)c*NT + s0 + sg*8];
            float sc = sS[c], tb = sT[c];
            unsigned int w4[4] = {pk.x, pk.y, pk.z, pk.w};
            #pragma unroll
            for (int h = 0; h < 4; ++h){
                rb[j][2*h]   = f2bf(fmaxf(fmaf(bf2f((u16)(w4[h] & 0xFFFF)), sc, tb), 0.0f));
                rb[j][2*h+1] = f2bf(fmaxf(fmaf(bf2f((u16)(w4[h] >> 16)),   sc, tb), 0.0f));
            }
        }
        #pragma unroll
        for (int i = 0; i < 8; ++i){
            int n15 = (sg & 1)*8 + i;
            int cb  = (nt*2 + kk)*64 + qd*16 + n15;
            unsigned int d[4];
            #pragma unroll
            for (int h = 0; h < 4; ++h)
                d[h] = (unsigned int)rb[2*h][i] | (((unsigned int)rb[2*h+1][i]) << 16);
            bfB[cb] = make_uint4(d[0], d[1], d[2], d[3]);
        }
    }
    __syncthreads();

    // MFMA: wave w computes channels 0..127 x samples w*64..w*64+63
    const int w = t >> 6, lane = t & 63;
    f32x4 acc[8][4];
    #pragma unroll
    for (int mt = 0; mt < 8; ++mt)
        #pragma unroll
        for (int tt = 0; tt < 4; ++tt)
            acc[mt][tt] = (f32x4){0.0f, 0.0f, 0.0f, 0.0f};

    #pragma unroll
    for (int kk = 0; kk < 2; ++kk){
        short8 af[8];
        #pragma unroll
        for (int mt = 0; mt < 8; ++mt)
            af[mt] = *((const short8*)&bfA[(mt*2 + kk)*64 + lane]);
        #pragma unroll
        for (int tt = 0; tt < 4; ++tt){
            int nt = w*4 + tt;
            short8 bfr = *((const short8*)&bfB[(nt*2 + kk)*64 + lane]);
            #pragma unroll
            for (int mt = 0; mt < 8; ++mt)
                acc[mt][tt] = __builtin_amdgcn_mfma_f32_16x16x32_bf16(af[mt], bfr, acc[mt][tt], 0, 0, 0);
        }
    }

    // epilogue: per (channel, k-group) max/min/sum/sq. Group = 32 samples =
    // two n-tiles (tt pair) x 16 lanes -> in-reg combine + 4-stage butterfly.
    const int quad = lane >> 4;
    const int gblk = blockIdx.x*8 + w*2;
    #pragma unroll
    for (int mt = 0; mt < 8; ++mt){
        #pragma unroll
        for (int gh = 0; gh < 2; ++gh){
            float mx[4], mn[4], sm[4], sq[4];
            #pragma unroll
            for (int r = 0; r < 4; ++r){
                float a0 = acc[mt][2*gh][r], a1 = acc[mt][2*gh+1][r];
                mx[r] = fmaxf(a0, a1); mn[r] = fminf(a0, a1);
                sm[r] = a0 + a1;       sq[r] = fmaf(a0, a0, a1*a1);
            }
            #pragma unroll
            for (int st = 1; st < 16; st <<= 1){
                #pragma unroll
                for (int r = 0; r < 4; ++r){
                    mx[r] = fmaxf(mx[r], __shfl_xor(mx[r], st, 64));
                    mn[r] = fminf(mn[r], __shfl_xor(mn[r], st, 64));
                    sm[r] += __shfl_xor(sm[r], st, 64);
                    sq[r] += __shfl_xor(sq[r], st, 64);
                }
            }
            if ((lane & 15) == 0){
                #pragma unroll
                for (int r = 0; r < 4; ++r){
                    int o = mt*16 + quad*4 + r;
                    size_t gi = (size_t)o*BM + gblk + gh;
                    gmax[gi] = mx[r];
                    gmin[gi] = mn[r];
                    atomicAdd(&sSum[o], sm[r]);
                    atomicAdd(&sSq[o],  sq[r]);
                }
            }
        }
    }
    __syncthreads();
    if (t < 128){
        atomicAdd(&gsum[t], sSum[t]);
        atomicAdd(&gsq[t],  sSq[t]);
    }
}

// ---------------------------------------------------------------------------
// per-channel sum/sumsq over stored y (bf16 channel-major), vectorized
// ---------------------------------------------------------------------------
__global__ __launch_bounds__(256) void k_stats(const u16* __restrict__ y,
                                               float* __restrict__ sum,
                                               float* __restrict__ sumsq){
    int c = blockIdx.x, chunk = blockIdx.y;
    size_t base = (size_t)c*NT + (size_t)chunk*16384;
    const uint2* p = (const uint2*)(y + base);
    float s = 0.0f, qq = 0.0f;
    for (int i = threadIdx.x; i < 4096; i += 256){
        uint2 v = p[i];
        float v0 = bf2f((u16)(v.x & 0xFFFF)), v1 = bf2f((u16)(v.x >> 16));
        float v2 = bf2f((u16)(v.y & 0xFFFF)), v3 = bf2f((u16)(v.y >> 16));
        s += v0 + v1 + v2 + v3;
        qq = fmaf(v0, v0, qq); qq = fmaf(v1, v1, qq);
        qq = fmaf(v2, v2, qq); qq = fmaf(v3, v3, qq);
    }
    #pragma unroll
    for (int off = 32; off > 0; off >>= 1){
        s  += __shfl_down(s,  off, 64);
        qq += __shfl_down(qq, off, 64);
    }
    __shared__ float aS[4], aQ[4];
    int wave = threadIdx.x >> 6, lane = threadIdx.x & 63;
    if (lane == 0){ aS[wave] = s; aQ[wave] = qq; }
    __syncthreads();
    if (threadIdx.x == 0){
        atomicAdd(&sum[c],   aS[0] + aS[1] + aS[2] + aS[3]);
        atomicAdd(&sumsq[c], aQ[0] + aQ[1] + aQ[2] + aQ[3]);
    }
}

// fold BN into affine: s = g*rsqrt(var+eps), t = b - mu*s
__global__ void k_fold(const float* __restrict__ sum, const float* __restrict__ sumsq,
                       const float* __restrict__ gW, const float* __restrict__ bW,
                       float* __restrict__ prm, int C){
    int c = threadIdx.x;
    if (c < C){
        const float inv = 1.0f / (float)NT;
        float mu  = sum[c] * inv;
        float var = sumsq[c] * inv - mu*mu;
        float sc  = gW[c] / sqrtf(var + 1e-5f);
        prm[c]     = sc;
        prm[C + c] = bW[c] - mu*sc;
    }
}

// out[b][o][m] = ReLU(s * (s>=0 ? gmax : gmin) + t)   -- f32 output
__global__ __launch_bounds__(256) void k_final(const float* __restrict__ gmax,
                                               const float* __restrict__ gmin,
                                               const float* __restrict__ prm,
                                               float* __restrict__ out){
    int bo = blockIdx.y;
    int b = bo >> 7, o = bo & 127;
    int m = blockIdx.x*256 + threadIdx.x;
    float sc = prm[o], tt = prm[128 + o];
    size_t i = (size_t)o*BM + b*M_ + m;
    float v = (sc >= 0.0f) ? gmax[i] : gmin[i];
    out[((size_t)(b*128 + o))*M_ + m] = fmaxf(fmaf(v, sc, tt), 0.0f);
}

// ---------------------------------------------------------------------------
extern "C" void kernel_launch(void* const* d_in, const int* in_sizes, int n_in,
                              void* d_out, int out_size, void* d_ws, size_t ws_size,
                              hipStream_t stream){
    const float* loc  = (const float*)d_in[0];
    const float* nloc = (const float*)d_in[1];
    const float* feat = (const float*)d_in[2];
    const float* W1   = (const float*)d_in[3];
    const float* g1   = (const float*)d_in[4];
    const float* b1   = (const float*)d_in[5];
    const float* W2   = (const float*)d_in[6];
    const float* g2   = (const float*)d_in[7];
    const float* b2   = (const float*)d_in[8];
    const float* W3   = (const float*)d_in[9];
    const float* g3   = (const float*)d_in[10];
    const float* b3   = (const float*)d_in[11];
    float* out = (float*)d_out;

    char* ws = (char*)d_ws;
    float* stats = (float*)ws;                       // 512 f @ 0
    float* prm1  = (float*)(ws + 2048);              // 128 f
    float* prm2  = (float*)(ws + 2048 + 512);        // 128 f
    float* prm3  = (float*)(ws + 2048 + 1024);       // 256 f -> ends 4096
    int*   idx   = (int*)(ws + 4096);                // 2 MB
    float* gmax  = (float*)(ws + 2101248);           // 8 MB [128][BM]
    float* gmin  = (float*)(ws + 10489856);          // 8 MB
    float* featT = (float*)(ws + 18878464);          // 16 MB [B][N][64]
    u16*   y1    = (u16*)(ws + 35655680);            // 64 MB [64][NT]
    u16*   y2    = (u16*)(ws + 102764544);           // 64 MB  (ws >= 170 MB proven)

    hipMemsetAsync(stats, 0, 2048, stream);

    k_feat<<<dim3(N_/64, B_), 256, 0, stream>>>(feat, featT);
    k_knn<<<B_*M_, 256, 0, stream>>>(loc, nloc, idx);

    k_conv1t<<<NT/256, 256, 0, stream>>>(idx, loc, nloc, featT, W1, y1);
    k_stats<<<dim3(64, 32), 256, 0, stream>>>(y1, stats + 0, stats + 64);
    k_fold<<<1, 128, 0, stream>>>(stats + 0, stats + 64, g1, b1, prm1, 64);

    k_conv2t<<<NT/256, 256, 0, stream>>>(y1, W2, prm1, y2);
    k_stats<<<dim3(64, 32), 256, 0, stream>>>(y2, stats + 128, stats + 192);
    k_fold<<<1, 128, 0, stream>>>(stats + 128, stats + 192, g2, b2, prm2, 64);

    k_conv3m<<<NT/256, 256, 0, stream>>>(y2, W3, prm2, stats + 256, stats + 384, gmax, gmin);
    k_fold<<<1, 128, 0, stream>>>(stats + 256, stats + 384, g3, b3, prm3, 128);

    k_final<<<dim3(M_/256, B_*128), 256, 0, stream>>>(gmax, gmin, prm3, out);
}

// Round 11
// 522.917 us; speedup vs baseline: 2.0591x; 1.1454x over previous
//
#include <hip/hip_runtime.h>
#include <stdint.h>

// Problem constants
#define B_   16
#define N_   4096
#define M_   1024
#define NT   (B_*M_*32)      // 524288 samples
#define BM   (B_*M_)         // 16384 (b,m) groups

typedef unsigned short u16;
typedef unsigned long long u64;
typedef __attribute__((ext_vector_type(8))) short short8;   // 8 bf16 (4 VGPRs)
typedef __attribute__((ext_vector_type(4))) float f32x4;    // MFMA C/D

__device__ __forceinline__ float bf2f(u16 u){
    return __uint_as_float(((unsigned int)u) << 16);
}
__device__ __forceinline__ u16 f2bf(float f){
    unsigned int u = __float_as_uint(f);
    return (u16)((u + 0x7FFFu + ((u >> 16) & 1u)) >> 16);
}

// ---------------------------------------------------------------------------
// features [B][64][N] f32 -> featT [B][N][64] f32
// ---------------------------------------------------------------------------
__global__ __launch_bounds__(256) void k_feat(const float* __restrict__ feat,
                                              float* __restrict__ featT){
    __shared__ float tile[64][65];
    int b  = blockIdx.y;
    int n0 = blockIdx.x * 64;
    for (int t = threadIdx.x; t < 4096; t += 256){
        int c = t >> 6, n = t & 63;
        tile[c][n] = feat[((size_t)(b*64 + c))*N_ + n0 + n];
    }
    __syncthreads();
    for (int t = threadIdx.x; t < 4096; t += 256){
        int n = t >> 6, c = t & 63;
        featT[((size_t)(b*N_) + n0 + n)*64 + c] = tile[c][n];
    }
}

// ---------------------------------------------------------------------------
// exact KNN (32 smallest of 4096): value-domain LINEAR bucket select.
// Monotone bucket map (trunc((d2-lo)*scale)) keeps selection exact:
// bucket<q => key < every bucket-q key. Spread ~16 keys/bucket kills the
// LDS same-address atomic serialization that MSB-radix suffered (exponent
// concentration). Per-wave replicated histograms cut contention 4x.
// Exact (key,index) candidate finish == lax.top_k set (downstream is
// order-invariant).
// ---------------------------------------------------------------------------
__global__ __launch_bounds__(256) void k_knn(const float* __restrict__ locF,
                                             const float* __restrict__ nlocF,
                                             int* __restrict__ idxOut){
    const int tid  = threadIdx.x;
    const int lane = tid & 63, wv = tid >> 6;
    const int q    = blockIdx.x;
    const int b    = q >> 10, m = q & 1023;

    float qx = nlocF[(size_t)(b*M_ + m)*3 + 0];
    float qy = nlocF[(size_t)(b*M_ + m)*3 + 1];
    float qz = nlocF[(size_t)(b*M_ + m)*3 + 2];
    float y2 = __fadd_rn(__fadd_rn(__fmul_rn(qx,qx), __fmul_rn(qy,qy)), __fmul_rn(qz,qz));

    unsigned int key[16];
    const float* lb = locF + (size_t)b*N_*3;
    #pragma unroll
    for (int i = 0; i < 16; ++i){
        int n = i*256 + tid;
        float lx = lb[n*3+0], ly = lb[n*3+1], lz = lb[n*3+2];
        float x2 = __fadd_rn(__fadd_rn(__fmul_rn(lx,lx), __fmul_rn(ly,ly)), __fmul_rn(lz,lz));
        float dt = __fadd_rn(__fadd_rn(__fmul_rn(qx,lx), __fmul_rn(qy,ly)), __fmul_rn(qz,lz));
        float d2 = __fsub_rn(__fadd_rn(y2, x2), __fmul_rn(2.0f, dt));
        d2 = fmaxf(d2, 0.0f);                  // uint order == float order
        key[i] = __float_as_uint(d2);
    }

    __shared__ unsigned int hist[4][256];      // per-wave replicated
    __shared__ float wmm[4][2];
    __shared__ u64 cand[128];
    __shared__ int sOut[32];
    __shared__ int outCnt, candCnt;

    // block min/max of d2
    float lmin = 3.4e38f, lmax = 0.0f;
    #pragma unroll
    for (int i = 0; i < 16; ++i){
        float kf = __uint_as_float(key[i]);
        lmin = fminf(lmin, kf); lmax = fmaxf(lmax, kf);
    }
    #pragma unroll
    for (int st = 1; st < 64; st <<= 1){
        lmin = fminf(lmin, __shfl_xor(lmin, st, 64));
        lmax = fmaxf(lmax, __shfl_xor(lmax, st, 64));
    }
    if (tid == 0){ outCnt = 0; candCnt = 0; }
    if (lane == 0){ wmm[wv][0] = lmin; wmm[wv][1] = lmax; }
    __syncthreads();
    float lo = fminf(fminf(wmm[0][0], wmm[1][0]), fminf(wmm[2][0], wmm[3][0]));
    float hi = fmaxf(fmaxf(wmm[0][1], wmm[1][1]), fmaxf(wmm[2][1], wmm[3][1]));

    unsigned int act = 0xFFFFu;                // per-key active mask
    int bkt[16];
    int R = 32;

    for (int lvl = 0; lvl < 8; ++lvl){
        float scale = 255.0f / fmaxf(hi - lo, 1e-35f);
        ((uint4*)hist)[tid] = make_uint4(0,0,0,0);       // zero 4 KB
        __syncthreads();
        #pragma unroll
        for (int i = 0; i < 16; ++i){
            if (act & (1u << i)){
                float kf = __uint_as_float(key[i]);
                int bb = (int)((kf - lo) * scale);
                bb = bb < 0 ? 0 : (bb > 255 ? 255 : bb);
                bkt[i] = bb;
                atomicAdd(&hist[wv][bb], 1u);
            }
        }
        __syncthreads();
        // redundant per-wave scan of 256 summed buckets
        uint4 ha = *(const uint4*)&hist[0][lane << 2];
        uint4 hb = *(const uint4*)&hist[1][lane << 2];
        uint4 hc = *(const uint4*)&hist[2][lane << 2];
        uint4 hd = *(const uint4*)&hist[3][lane << 2];
        uint4 h = make_uint4(ha.x+hb.x+hc.x+hd.x, ha.y+hb.y+hc.y+hd.y,
                             ha.z+hb.z+hc.z+hd.z, ha.w+hb.w+hc.w+hd.w);
        int tot = (int)(h.x + h.y + h.z + h.w);
        int v = tot;
        #pragma unroll
        for (int st = 1; st < 64; st <<= 1){
            int u = __shfl_up(v, st, 64);
            if (lane >= st) v += u;
        }
        u64 bal = __ballot(v >= R);
        int Ls = __ffsll((unsigned long long)bal) - 1;
        int exclS = __shfl(v - tot, Ls, 64);
        int hx = __shfl((int)h.x, Ls, 64), hy = __shfl((int)h.y, Ls, 64);
        int hz = __shfl((int)h.z, Ls, 64), hw = __shfl((int)h.w, Ls, 64);
        int c0 = exclS + hx, c1 = c0 + hy, c2 = c1 + hz;
        int jj    = (c0 >= R) ? 0 : (c1 >= R) ? 1 : (c2 >= R) ? 2 : 3;
        int below = (jj == 0) ? exclS : (jj == 1) ? c0 : (jj == 2) ? c1 : c2;
        int cnt   = (jj == 0) ? hx : (jj == 1) ? hy : (jj == 2) ? hz : hw;
        int qb = Ls*4 + jj;
        R -= below;
        bool brk = (cnt <= 128) || (lvl == 7);

        float nlo = 3.4e38f, nhi = 0.0f;
        #pragma unroll
        for (int i = 0; i < 16; ++i){
            if (act & (1u << i)){
                int bb = bkt[i];
                if (bb < qb){                           // definitely in top-32
                    int pos = atomicAdd(&outCnt, 1);
                    if (pos < 32) sOut[pos] = i*256 + tid;
                    act &= ~(1u << i);
                } else if (bb > qb){                    // definitely out
                    act &= ~(1u << i);
                } else if (!brk){
                    float kf = __uint_as_float(key[i]);
                    nlo = fminf(nlo, kf); nhi = fmaxf(nhi, kf);
                }
            }
        }
        if (brk) break;
        #pragma unroll
        for (int st = 1; st < 64; st <<= 1){
            nlo = fminf(nlo, __shfl_xor(nlo, st, 64));
            nhi = fmaxf(nhi, __shfl_xor(nhi, st, 64));
        }
        __syncthreads();
        if (lane == 0){ wmm[wv][0] = nlo; wmm[wv][1] = nhi; }
        __syncthreads();
        lo = fminf(fminf(wmm[0][0], wmm[1][0]), fminf(wmm[2][0], wmm[3][0]));
        hi = fmaxf(fmaxf(wmm[0][1], wmm[1][1]), fmaxf(wmm[2][1], wmm[3][1]));
    }

    // candidates = still-active keys (pivot bucket), exact (key,idx) rank
    #pragma unroll
    for (int i = 0; i < 16; ++i){
        if (act & (1u << i)){
            int pos = atomicAdd(&candCnt, 1);
            if (pos < 128) cand[pos] = (((u64)key[i]) << 32) | (unsigned int)(i*256 + tid);
        }
    }
    __syncthreads();
    int c = candCnt < 128 ? candCnt : 128;
    int base = outCnt;                         // == 32 - R
    if (tid < c){
        u64 me = cand[tid];
        int rank = 0;
        for (int j = 0; j < c; ++j) rank += (cand[j] < me) ? 1 : 0;
        if (rank < R) sOut[base + rank] = (int)(me & 0xFFFFFFFFull);
    }
    __syncthreads();
    if (tid < 32) idxOut[(size_t)q*32 + tid] = sOut[tid];
}

// ---------------------------------------------------------------------------
// conv1 tiled: thread = (o-block 16, s-block 4); gather staged via LDS.
// ---------------------------------------------------------------------------
__global__ __launch_bounds__(256) void k_conv1t(const int* __restrict__ idx,
                                                const float* __restrict__ locF,
                                                const float* __restrict__ nlocF,
                                                const float* __restrict__ featT,
                                                const float* __restrict__ W1,
                                                u16* __restrict__ y1){
    __shared__ float Wl[67*64];     // [c][o]
    __shared__ float At[16*256];    // [c_local][s_local]
    const int t  = threadIdx.x;
    const int s0 = blockIdx.x * 256;
    for (int i = t; i < 67*64; i += 256){
        int c = i >> 6, o = i & 63;
        Wl[i] = W1[o*67 + c];
    }
    __syncthreads();

    const int ob = t >> 6;
    const int sb = t & 63;
    const int o0 = ob*16;
    const int b  = s0 >> 15;
    float acc[16][4];

    {
        int4 nn = *(const int4*)&idx[s0 + sb*4];
        int ns[4] = {nn.x, nn.y, nn.z, nn.w};
        int m = ((s0 + sb*4) >> 5) & 1023;
        float qx = nlocF[(size_t)(b*M_ + m)*3 + 0];
        float qy = nlocF[(size_t)(b*M_ + m)*3 + 1];
        float qz = nlocF[(size_t)(b*M_ + m)*3 + 2];
        float r0[4], r1[4], r2[4];
        #pragma unroll
        for (int j = 0; j < 4; ++j){
            int n = ns[j]; if ((unsigned)n >= N_) n = 0;
            const float* lp = &locF[(size_t)(b*N_ + n)*3];
            r0[j] = lp[0] - qx; r1[j] = lp[1] - qy; r2[j] = lp[2] - qz;
        }
        #pragma unroll
        for (int i = 0; i < 16; ++i){
            float w0 = Wl[o0 + i], w1 = Wl[64 + o0 + i], w2 = Wl[128 + o0 + i];
            #pragma unroll
            for (int j = 0; j < 4; ++j)
                acc[i][j] = fmaf(w2, r2[j], fmaf(w1, r1[j], w0*r0[j]));
        }
    }

    for (int pass = 0; pass < 4; ++pass){
        __syncthreads();
        {
            int n = idx[s0 + t]; if ((unsigned)n >= N_) n = 0;
            const float4* fr = (const float4*)&featT[((size_t)(b*N_) + n)*64 + pass*16];
            #pragma unroll
            for (int q = 0; q < 4; ++q){
                float4 f = fr[q];
                At[(q*4+0)*256 + t] = f.x;
                At[(q*4+1)*256 + t] = f.y;
                At[(q*4+2)*256 + t] = f.z;
                At[(q*4+3)*256 + t] = f.w;
            }
        }
        __syncthreads();
        const float4* Wrow = (const float4*)&Wl[(3 + pass*16)*64];
        #pragma unroll
        for (int c = 0; c < 16; ++c){
            float4 a = *(const float4*)&At[c*256 + sb*4];
            float av[4] = {a.x, a.y, a.z, a.w};
            #pragma unroll
            for (int q = 0; q < 4; ++q){
                float4 w = Wrow[c*16 + ob*4 + q];
                float wv[4] = {w.x, w.y, w.z, w.w};
                #pragma unroll
                for (int r = 0; r < 4; ++r)
                    #pragma unroll
                    for (int j = 0; j < 4; ++j)
                        acc[q*4+r][j] = fmaf(wv[r], av[j], acc[q*4+r][j]);
            }
        }
    }
    #pragma unroll
    for (int i = 0; i < 16; ++i){
        ushort4 pk;
        pk.x = f2bf(acc[i][0]); pk.y = f2bf(acc[i][1]);
        pk.z = f2bf(acc[i][2]); pk.w = f2bf(acc[i][3]);
        *(ushort4*)&y1[(size_t)(o0+i)*NT + s0 + sb*4] = pk;
    }
}

// ---------------------------------------------------------------------------
// conv2 tiled
// ---------------------------------------------------------------------------
__global__ __launch_bounds__(256) void k_conv2t(const u16* __restrict__ yin,
                                                const float* __restrict__ W2,
                                                const float* __restrict__ prm,
                                                u16* __restrict__ yout){
    __shared__ float Wl[64*64];     // [c][o]
    __shared__ float At[16*256];
    __shared__ float sS[64], sT[64];
    const int t  = threadIdx.x;
    const int s0 = blockIdx.x * 256;
    for (int i = t; i < 64*64; i += 256){
        int c = i >> 6, o = i & 63;
        Wl[i] = W2[o*64 + c];
    }
    if (t < 64){ sS[t] = prm[t]; sT[t] = prm[64 + t]; }

    const int ob = t >> 6, sb = t & 63, o0 = ob*16;
    float acc[16][4];
    #pragma unroll
    for (int i = 0; i < 16; ++i)
        #pragma unroll
        for (int j = 0; j < 4; ++j) acc[i][j] = 0.0f;

    for (int pass = 0; pass < 4; ++pass){
        __syncthreads();
        #pragma unroll
        for (int rep = 0; rep < 2; ++rep){
            int v = rep*256 + t;
            int row = v >> 5, ch = v & 31;
            int c = pass*16 + row;
            uint4 pk = *(const uint4*)&yin[(size_t)c*NT + s0 + ch*8];
            float sc = sS[c], tt = sT[c];
            unsigned int w4[4] = {pk.x, pk.y, pk.z, pk.w};
            float f[8];
            #pragma unroll
            for (int q = 0; q < 4; ++q){
                f[2*q]   = fmaxf(fmaf(bf2f((u16)(w4[q] & 0xFFFF)), sc, tt), 0.0f);
                f[2*q+1] = fmaxf(fmaf(bf2f((u16)(w4[q] >> 16)),   sc, tt), 0.0f);
            }
            float4 f1 = {f[0], f[1], f[2], f[3]};
            float4 f2 = {f[4], f[5], f[6], f[7]};
            *(float4*)&At[row*256 + ch*8]     = f1;
            *(float4*)&At[row*256 + ch*8 + 4] = f2;
        }
        __syncthreads();
        const float4* Wrow = (const float4*)&Wl[(pass*16)*64];
        #pragma unroll
        for (int c = 0; c < 16; ++c){
            float4 a = *(const float4*)&At[c*256 + sb*4];
            float av[4] = {a.x, a.y, a.z, a.w};
            #pragma unroll
            for (int q = 0; q < 4; ++q){
                float4 w = Wrow[c*16 + ob*4 + q];
                float wv[4] = {w.x, w.y, w.z, w.w};
                #pragma unroll
                for (int r = 0; r < 4; ++r)
                    #pragma unroll
                    for (int j = 0; j < 4; ++j)
                        acc[q*4+r][j] = fmaf(wv[r], av[j], acc[q*4+r][j]);
            }
        }
    }
    #pragma unroll
    for (int i = 0; i < 16; ++i){
        ushort4 pk;
        pk.x = f2bf(acc[i][0]); pk.y = f2bf(acc[i][1]);
        pk.z = f2bf(acc[i][2]); pk.w = f2bf(acc[i][3]);
        *(ushort4*)&yout[(size_t)(o0+i)*NT + s0 + sb*4] = pk;
    }
}

// ---------------------------------------------------------------------------
// conv3 via MFMA (bf16 in, f32 acc) + fused stats/minmax.
// ---------------------------------------------------------------------------
__global__ __launch_bounds__(256) void k_conv3m(const u16* __restrict__ yin,
                                                const float* __restrict__ W3,
                                                const float* __restrict__ prm,
                                                float* __restrict__ gsum, float* __restrict__ gsq,
                                                float* __restrict__ gmax, float* __restrict__ gmin){
    __shared__ uint4 bfA[1024];     // W3 bf16 frags: (mt*2+kk)*64+lane   (16 KB)
    __shared__ uint4 bfB[2048];     // act bf16 frags: (nt*2+kk)*64+lane  (32 KB)
    __shared__ float sS[64], sT[64];
    __shared__ float sSum[128], sSq[128];
    const int t  = threadIdx.x;
    const int s0 = blockIdx.x * 256;

    if (t < 64){ sS[t] = prm[t]; sT[t] = prm[64 + t]; }
    if (t < 128){ sSum[t] = 0.0f; sSq[t] = 0.0f; }
    __syncthreads();

    // stage A: W3 [128][64] f32 -> bf16 frags
    #pragma unroll
    for (int rep = 0; rep < 4; ++rep){
        int cid = rep*256 + t;
        int ln  = cid & 63;
        int kk  = (cid >> 6) & 1;
        int mt  = cid >> 7;
        int m   = mt*16 + (ln & 15);
        int k0  = kk*32 + (ln >> 4)*8;
        const float* wp = &W3[m*64 + k0];
        unsigned int d[4];
        #pragma unroll
        for (int h = 0; h < 4; ++h)
            d[h] = (unsigned int)f2bf(wp[2*h]) | (((unsigned int)f2bf(wp[2*h+1])) << 16);
        bfA[cid] = make_uint4(d[0], d[1], d[2], d[3]);
    }

    // stage B: y2 channel-major, coalesced load; affine+relu; bf16 frags
    {
        int oct = t >> 5;
        int sg  = t & 31;
        int c0  = oct*8;
        int kk  = oct >> 2;
        int qd  = oct & 3;
        int nt  = sg >> 1;
        u16 rb[8][8];
        #pragma unroll
        for (int j = 0; j < 8; ++j){
            int c = c0 + j;
            uint4 pk = *(const uint4*)&yin[(size_t)c*NT + s0 + sg*8];
            float sc = sS[c], tb = sT[c];
            unsigned int w4[4] = {pk.x, pk.y, pk.z, pk.w};
            #pragma unroll
            for (int h = 0; h < 4; ++h){
                rb[j][2*h]   = f2bf(fmaxf(fmaf(bf2f((u16)(w4[h] & 0xFFFF)), sc, tb), 0.0f));
                rb[j][2*h+1] = f2bf(fmaxf(fmaf(bf2f((u16)(w4[h] >> 16)),   sc, tb), 0.0f));
            }
        }
        #pragma unroll
        for (int i = 0; i < 8; ++i){
            int n15 = (sg & 1)*8 + i;
            int cb  = (nt*2 + kk)*64 + qd*16 + n15;
            unsigned int d[4];
            #pragma unroll
            for (int h = 0; h < 4; ++h)
                d[h] = (unsigned int)rb[2*h][i] | (((unsigned int)rb[2*h+1][i]) << 16);
            bfB[cb] = make_uint4(d[0], d[1], d[2], d[3]);
        }
    }
    __syncthreads();

    const int w = t >> 6, lane = t & 63;
    f32x4 acc[8][4];
    #pragma unroll
    for (int mt = 0; mt < 8; ++mt)
        #pragma unroll
        for (int tt = 0; tt < 4; ++tt)
            acc[mt][tt] = (f32x4){0.0f, 0.0f, 0.0f, 0.0f};

    #pragma unroll
    for (int kk = 0; kk < 2; ++kk){
        short8 af[8];
        #pragma unroll
        for (int mt = 0; mt < 8; ++mt)
            af[mt] = *((const short8*)&bfA[(mt*2 + kk)*64 + lane]);
        #pragma unroll
        for (int tt = 0; tt < 4; ++tt){
            int nt = w*4 + tt;
            short8 bfr = *((const short8*)&bfB[(nt*2 + kk)*64 + lane]);
            #pragma unroll
            for (int mt = 0; mt < 8; ++mt)
                acc[mt][tt] = __builtin_amdgcn_mfma_f32_16x16x32_bf16(af[mt], bfr, acc[mt][tt], 0, 0, 0);
        }
    }

    const int quad = lane >> 4;
    const int gblk = blockIdx.x*8 + w*2;
    #pragma unroll
    for (int mt = 0; mt < 8; ++mt){
        #pragma unroll
        for (int gh = 0; gh < 2; ++gh){
            float mx[4], mn[4], sm[4], sq[4];
            #pragma unroll
            for (int r = 0; r < 4; ++r){
                float a0 = acc[mt][2*gh][r], a1 = acc[mt][2*gh+1][r];
                mx[r] = fmaxf(a0, a1); mn[r] = fminf(a0, a1);
                sm[r] = a0 + a1;       sq[r] = fmaf(a0, a0, a1*a1);
            }
            #pragma unroll
            for (int st = 1; st < 16; st <<= 1){
                #pragma unroll
                for (int r = 0; r < 4; ++r){
                    mx[r] = fmaxf(mx[r], __shfl_xor(mx[r], st, 64));
                    mn[r] = fminf(mn[r], __shfl_xor(mn[r], st, 64));
                    sm[r] += __shfl_xor(sm[r], st, 64);
                    sq[r] += __shfl_xor(sq[r], st, 64);
                }
            }
            if ((lane & 15) == 0){
                #pragma unroll
                for (int r = 0; r < 4; ++r){
                    int o = mt*16 + quad*4 + r;
                    size_t gi = (size_t)o*BM + gblk + gh;
                    gmax[gi] = mx[r];
                    gmin[gi] = mn[r];
                    atomicAdd(&sSum[o], sm[r]);
                    atomicAdd(&sSq[o],  sq[r]);
                }
            }
        }
    }
    __syncthreads();
    if (t < 128){
        atomicAdd(&gsum[t], sSum[t]);
        atomicAdd(&gsq[t],  sSq[t]);
    }
}

// ---------------------------------------------------------------------------
// per-channel sum/sumsq over stored y (bf16 channel-major), vectorized
// ---------------------------------------------------------------------------
__global__ __launch_bounds__(256) void k_stats(const u16* __restrict__ y,
                                               float* __restrict__ sum,
                                               float* __restrict__ sumsq){
    int c = blockIdx.x, chunk = blockIdx.y;
    size_t base = (size_t)c*NT + (size_t)chunk*16384;
    const uint2* p = (const uint2*)(y + base);
    float s = 0.0f, qq = 0.0f;
    for (int i = threadIdx.x; i < 4096; i += 256){
        uint2 v = p[i];
        float v0 = bf2f((u16)(v.x & 0xFFFF)), v1 = bf2f((u16)(v.x >> 16));
        float v2 = bf2f((u16)(v.y & 0xFFFF)), v3 = bf2f((u16)(v.y >> 16));
        s += v0 + v1 + v2 + v3;
        qq = fmaf(v0, v0, qq); qq = fmaf(v1, v1, qq);
        qq = fmaf(v2, v2, qq); qq = fmaf(v3, v3, qq);
    }
    #pragma unroll
    for (int off = 32; off > 0; off >>= 1){
        s  += __shfl_down(s,  off, 64);
        qq += __shfl_down(qq, off, 64);
    }
    __shared__ float aS[4], aQ[4];
    int wave = threadIdx.x >> 6, lane = threadIdx.x & 63;
    if (lane == 0){ aS[wave] = s; aQ[wave] = qq; }
    __syncthreads();
    if (threadIdx.x == 0){
        atomicAdd(&sum[c],   aS[0] + aS[1] + aS[2] + aS[3]);
        atomicAdd(&sumsq[c], aQ[0] + aQ[1] + aQ[2] + aQ[3]);
    }
}

// fold BN into affine: s = g*rsqrt(var+eps), t = b - mu*s
__global__ void k_fold(const float* __restrict__ sum, const float* __restrict__ sumsq,
                       const float* __restrict__ gW, const float* __restrict__ bW,
                       float* __restrict__ prm, int C){
    int c = threadIdx.x;
    if (c < C){
        const float inv = 1.0f / (float)NT;
        float mu  = sum[c] * inv;
        float var = sumsq[c] * inv - mu*mu;
        float sc  = gW[c] / sqrtf(var + 1e-5f);
        prm[c]     = sc;
        prm[C + c] = bW[c] - mu*sc;
    }
}

// out[b][o][m] = ReLU(s * (s>=0 ? gmax : gmin) + t)   -- f32 output
__global__ __launch_bounds__(256) void k_final(const float* __restrict__ gmax,
                                               const float* __restrict__ gmin,
                                               const float* __restrict__ prm,
                                               float* __restrict__ out){
    int bo = blockIdx.y;
    int b = bo >> 7, o = bo & 127;
    int m = blockIdx.x*256 + threadIdx.x;
    float sc = prm[o], tt = prm[128 + o];
    size_t i = (size_t)o*BM + b*M_ + m;
    float v = (sc >= 0.0f) ? gmax[i] : gmin[i];
    out[((size_t)(b*128 + o))*M_ + m] = fmaxf(fmaf(v, sc, tt), 0.0f);
}

// ---------------------------------------------------------------------------
extern "C" void kernel_launch(void* const* d_in, const int* in_sizes, int n_in,
                              void* d_out, int out_size, void* d_ws, size_t ws_size,
                              hipStream_t stream){
    const float* loc  = (const float*)d_in[0];
    const float* nloc = (const float*)d_in[1];
    const float* feat = (const float*)d_in[2];
    const float* W1   = (const float*)d_in[3];
    const float* g1   = (const float*)d_in[4];
    const float* b1   = (const float*)d_in[5];
    const float* W2   = (const float*)d_in[6];
    const float* g2   = (const float*)d_in[7];
    const float* b2   = (const float*)d_in[8];
    const float* W3   = (const float*)d_in[9];
    const float* g3   = (const float*)d_in[10];
    const float* b3   = (const float*)d_in[11];
    float* out = (float*)d_out;

    char* ws = (char*)d_ws;
    float* stats = (float*)ws;                       // 512 f @ 0
    float* prm1  = (float*)(ws + 2048);              // 128 f
    float* prm2  = (float*)(ws + 2048 + 512);        // 128 f
    float* prm3  = (float*)(ws + 2048 + 1024);       // 256 f -> ends 4096
    int*   idx   = (int*)(ws + 4096);                // 2 MB
    float* gmax  = (float*)(ws + 2101248);           // 8 MB [128][BM]
    float* gmin  = (float*)(ws + 10489856);          // 8 MB
    float* featT = (float*)(ws + 18878464);          // 16 MB [B][N][64]
    u16*   y1    = (u16*)(ws + 35655680);            // 64 MB [64][NT]
    u16*   y2    = (u16*)(ws + 102764544);           // 64 MB  (ws >= 170 MB proven)

    hipMemsetAsync(stats, 0, 2048, stream);

    k_feat<<<dim3(N_/64, B_), 256, 0, stream>>>(feat, featT);
    k_knn<<<B_*M_, 256, 0, stream>>>(loc, nloc, idx);

    k_conv1t<<<NT/256, 256, 0, stream>>>(idx, loc, nloc, featT, W1, y1);
    k_stats<<<dim3(64, 32), 256, 0, stream>>>(y1, stats + 0, stats + 64);
    k_fold<<<1, 128, 0, stream>>>(stats + 0, stats + 64, g1, b1, prm1, 64);

    k_conv2t<<<NT/256, 256, 0, stream>>>(y1, W2, prm1, y2);
    k_stats<<<dim3(64, 32), 256, 0, stream>>>(y2, stats + 128, stats + 192);
    k_fold<<<1, 128, 0, stream>>>(stats + 128, stats + 192, g2, b2, prm2, 64);

    k_conv3m<<<NT/256, 256, 0, stream>>>(y2, W3, prm2, stats + 256, stats + 384, gmax, gmin);
    k_fold<<<1, 128, 0, stream>>>(stats + 256, stats + 384, g3, b3, prm3, 128);

    k_final<<<dim3(M_/256, B_*128), 256, 0, stream>>>(gmax, gmin, prm3, out);
}